// Round 12
// baseline (1468.747 us; speedup 1.0000x reference)
//
#include <hip/hip_runtime.h>
#include <hip/hip_bf16.h>

// Problem constants
#define Bb 256
#define Nn_ 17
#define CIN 3
#define HID 64
#define CCH 128        // HEADS*HID
#define Gg 16384       // B*S
#define Ee 81          // 64 edges + 17 self loops
#define LSTM_IN 2176   // 17*128
#define OUT_ 128
#define G4 512         // 4*OUT
#define NCLS 10
#define Tt 64
#define Mg (Gg * Nn_)  // 278528
#define GPB8 8         // graphs per fused block
#define RB 136         // real rows per block (8*17)
#define RT 144         // padded rows (9 MFMA m-tiles)

typedef unsigned short u16;
typedef unsigned int u32;
typedef __attribute__((ext_vector_type(8))) short bf16x8;
typedef __attribute__((ext_vector_type(4))) float f32x4;

__device__ __forceinline__ u16 f2bf(float f) {   // RNE fp32->bf16
    u32 u = __float_as_uint(f);
    u += 0x7fffu + ((u >> 16) & 1u);
    return (u16)(u >> 16);
}
__device__ __forceinline__ float bflo(u32 v) { return __uint_as_float(v << 16); }
__device__ __forceinline__ float bfhi(u32 v) { return __uint_as_float(v & 0xffff0000u); }

__device__ __forceinline__ void async16(const void* g, void* l) {
    __builtin_amdgcn_global_load_lds((__attribute__((address_space(1))) u32*)g,
                                     (__attribute__((address_space(3))) u32*)l, 16, 0, 0);
}

// ---------------- setup: build src/dst + dst-CSR
__global__ void k_setup(const int* __restrict__ edge_index, int* __restrict__ csr) {
    if (threadIdx.x == 0 && blockIdx.x == 0) {
        int* src = csr;                    // [81]
        int* dst = csr + Ee;               // [81]
        int* off = csr + 2 * Ee;           // [18]
        int* eid = csr + 2 * Ee + Nn_ + 1; // [81]
        for (int e = 0; e < 64; e++) { src[e] = edge_index[e]; dst[e] = edge_index[64 + e]; }
        for (int n = 0; n < Nn_; n++) { src[64 + n] = n; dst[64 + n] = n; }
        int cnt[Nn_];
        for (int n = 0; n < Nn_; n++) cnt[n] = 0;
        for (int e = 0; e < Ee; e++) cnt[dst[e]]++;
        off[0] = 0;
        for (int n = 0; n < Nn_; n++) off[n + 1] = off[n] + cnt[n];
        int pos[Nn_];
        for (int n = 0; n < Nn_; n++) pos[n] = off[n];
        for (int e = 0; e < Ee; e++) eid[pos[dst[e]]++] = e;
    }
}

__global__ void k_convert(const float* __restrict__ in, u16* __restrict__ out, long n) {
    long i = (long)blockIdx.x * 256 + threadIdx.x;
    if (i < n) out[i] = f2bf(in[i]);
}
// 128x128 weight: [k][n] -> bf16 [n][k] (transpose for MFMA B-operand)
__global__ void k_convert_t128(const float* __restrict__ in, u16* __restrict__ out) {
    int i = blockIdx.x * 256 + threadIdx.x;  // over 16384
    int n = i >> 7, k = i & 127;
    out[i] = f2bf(in[k * 128 + n]);
}

// ================ shared attention phase (operates on LDS state) ================
// hT: [RT][128] bf16, XOR-chunk swizzle (chunk' = chunk ^ (row&15))
// asd: [RB][4] fp32 dots (src_h0, src_h1, dst_h0, dst_h1)
// Writes final h (bias+softmax-aggregated, optional relu) back to hT, then to hgOut.
__device__ __forceinline__ void gat_attn_lds(
    u16* hT, float* asd, float (*ev)[162], float (*mS)[34], float (*dS)[34],
    const float* bvec, const int* srcS, const int* dstS,
    const int* offS, const int* eidS,
    int t, int relu_flag, u32* hgOut) {
    __syncthreads();   // h + asd writes visible
    // edge scores + leaky relu: 1296 items
    for (int i = t; i < GPB8 * 162; i += 256) {
        const int g = i / 162, rem = i % 162, e = rem >> 1, hh = rem & 1;
        float v = asd[(g * Nn_ + srcS[e]) * 4 + hh] + asd[(g * Nn_ + dstS[e]) * 4 + 2 + hh];
        ev[g][rem] = (v > 0.f) ? v : 0.2f * v;
    }
    __syncthreads();
    // per-node max/den: 272 items (full-coverage loop -- r8 bug class)
    for (int i = t; i < GPB8 * 34; i += 256) {
        const int g = i / 34, rem = i % 34, n = rem >> 1, hh = rem & 1;
        const int p0 = offS[n], p1 = offS[n + 1];
        float m = -1e30f;
        for (int p = p0; p < p1; p++) m = fmaxf(m, ev[g][eidS[p] * 2 + hh]);
        float den = 0.f;
        for (int p = p0; p < p1; p++) den += expf(ev[g][eidS[p] * 2 + hh] - m);
        mS[g][rem] = m;
        dS[g][rem] = den;
    }
    __syncthreads();
    // alpha: 1296 items
    for (int i = t; i < GPB8 * 162; i += 256) {
        const int g = i / 162, rem = i % 162, e = rem >> 1, hh = rem & 1;
        const int n = dstS[e];
        ev[g][rem] = expf(ev[g][rem] - mS[g][n * 2 + hh]) / (dS[g][n * 2 + hh] + 1e-16f);
    }
    __syncthreads();
    // aggregation: 2 half-passes, reg-buffered across a barrier (in-place over hT)
#pragma unroll 1
    for (int hh = 0; hh < 2; hh++) {
        float ac0[17], ac1[17];
#pragma unroll
        for (int it = 0; it < 17; it++) {
            const int i = t + it * 256;          // < 4352
            const int cp = i & 31, rest = i >> 5;
            const int n = rest % 17, g = rest / 17;
            const int c = hh * 64 + cp * 2;
            const int p0 = offS[n], p1 = offS[n + 1];
            float a0 = 0.f, a1 = 0.f;
            for (int p = p0; p < p1; p++) {
                const int e = eidS[p];
                const int sr = g * Nn_ + srcS[e];
                const u32 hv = *(const u32*)&hT[sr * 128 + ((((c >> 3)) ^ (sr & 15)) << 3) + (c & 7)];
                const float al = ev[g][e * 2 + hh];
                a0 += al * bflo(hv);
                a1 += al * bfhi(hv);
            }
            a0 += bvec[c];
            a1 += bvec[c + 1];
            if (relu_flag) { a0 = fmaxf(a0, 0.f); a1 = fmaxf(a1, 0.f); }
            ac0[it] = a0;
            ac1[it] = a1;
        }
        __syncthreads();   // all reads of old h done
#pragma unroll
        for (int it = 0; it < 17; it++) {
            const int i = t + it * 256;
            const int cp = i & 31, rest = i >> 5;
            const int n = rest % 17, g = rest / 17;
            const int c = hh * 64 + cp * 2;
            const int row = g * Nn_ + n;
            *(u32*)&hT[row * 128 + ((((c >> 3)) ^ (row & 15)) << 3) + (c & 7)] =
                (u32)f2bf(ac0[it]) | ((u32)f2bf(ac1[it]) << 16);
        }
        __syncthreads();
    }
    // final write: coalesced u32 rows
    for (int i = t; i < RB * 64; i += 256) {
        const int row = i >> 6, cp = i & 63, c = cp * 2;
        hgOut[i] = *(const u32*)&hT[row * 128 + ((((c >> 3)) ^ (row & 15)) << 3) + (c & 7)];
    }
}

// ================ fused GAT layer (L>=1): GEMM (LDS A, L2 B) + dots + attention ================
__global__ __launch_bounds__(256) void k_gatfused(u16* __restrict__ HB,
                                                  const u16* __restrict__ Wt,
                                                  const float* __restrict__ a_src,
                                                  const float* __restrict__ a_dst,
                                                  const float* __restrict__ bias,
                                                  const int* __restrict__ csr,
                                                  int relu_flag) {
    __shared__ __align__(16) u16 hT[RT * 128];      // 36,864 B
    __shared__ float asd[RB * 4];
    __shared__ float ev[GPB8][162];
    __shared__ float mS[GPB8][34], dS[GPB8][34];
    __shared__ float avec[128], dvec[128], bvec[128];
    __shared__ int srcS[Ee], dstS[Ee], offS[Nn_ + 1], eidS[Ee];
    const int t = threadIdx.x;
    const int w = t >> 6, lane = t & 63, q = lane >> 4, col = lane & 15;
    const long bm = (long)blockIdx.x * RB;

    if (t < Ee) { srcS[t] = csr[t]; dstS[t] = csr[Ee + t]; eidS[t] = csr[180 + t]; }
    if (t >= 128 && t < 128 + Nn_ + 1) offS[t - 128] = csr[162 + t - 128];
    if (t < 128) { avec[t] = a_src[t]; bvec[t] = bias[t]; }
    else dvec[t - 128] = a_dst[t - 128];

    // stage A: 2304 16B-chunks (136 real rows async, 8 pad rows zero)
#pragma unroll
    for (int i = 0; i < 9; i++) {
        const int slot = (i * 4 + w) * 64 + lane;
        const int r = slot >> 4, cs = slot & 15;
        if (r < RB) {
            const int cg = cs ^ (r & 15);
            async16(HB + (bm + r) * 128 + cg * 8, &hT[slot * 8]);
        } else {
            *(uint4*)&hT[slot * 8] = make_uint4(0, 0, 0, 0);
        }
    }
    __syncthreads();

    // GEMM: 9 m-tiles distributed over 4 waves; B-frags from L2-hot 32 KB Wt
    for (int mt = w; mt < 9; mt += 4) {
        const int rowA = mt * 16 + col;
        bf16x8 af[4];
#pragma unroll
        for (int ks = 0; ks < 4; ks++)
            af[ks] = *(const bf16x8*)&hT[rowA * 128 + (((ks * 4 + q) ^ (rowA & 15)) << 3)];
        f32x4 acc[8] = {};
#pragma unroll
        for (int ks = 0; ks < 4; ks++)
#pragma unroll
            for (int nt = 0; nt < 8; nt++) {
                bf16x8 bf = *(const bf16x8*)&Wt[(nt * 16 + col) * 128 + (ks * 4 + q) * 8];
                acc[nt] = __builtin_amdgcn_mfma_f32_16x16x32_bf16(af[ks], bf, acc[nt], 0, 0, 0);
            }
        // epilogue: write h back (own rows only) + fp32 dots
#pragma unroll
        for (int nt = 0; nt < 8; nt++) {
            const int c = nt * 16 + col;
#pragma unroll
            for (int r = 0; r < 4; r++) {
                const int row = mt * 16 + q * 4 + r;
                hT[row * 128 + ((((c >> 3)) ^ (row & 15)) << 3) + (c & 7)] = f2bf(acc[nt][r]);
            }
        }
#pragma unroll
        for (int r = 0; r < 4; r++) {
            float s0 = 0.f, s1 = 0.f, d0 = 0.f, d1 = 0.f;
#pragma unroll
            for (int nt = 0; nt < 4; nt++) {
                const float v = acc[nt][r];
                s0 += v * avec[nt * 16 + col];
                d0 += v * dvec[nt * 16 + col];
            }
#pragma unroll
            for (int nt = 4; nt < 8; nt++) {
                const float v = acc[nt][r];
                s1 += v * avec[nt * 16 + col];
                d1 += v * dvec[nt * 16 + col];
            }
#pragma unroll
            for (int o = 1; o < 16; o <<= 1) {
                s0 += __shfl_xor(s0, o);
                s1 += __shfl_xor(s1, o);
                d0 += __shfl_xor(d0, o);
                d1 += __shfl_xor(d1, o);
            }
            const int row = mt * 16 + q * 4 + r;
            if (col == 0 && row < RB) {
                asd[row * 4 + 0] = s0;
                asd[row * 4 + 1] = s1;
                asd[row * 4 + 2] = d0;
                asd[row * 4 + 3] = d1;
            }
        }
    }
    gat_attn_lds(hT, asd, ev, mS, dS, bvec, srcS, dstS, offS, eidS, t, relu_flag,
                 (u32*)HB + bm * 64);
}

// ================ fused GAT layer 0: x@W0 projection + dots + attention ================
__global__ __launch_bounds__(256) void k_l0attn(const float* __restrict__ x,
                                                const float* __restrict__ W0,
                                                const float* __restrict__ gas0,
                                                const float* __restrict__ gad0,
                                                const float* __restrict__ bias,
                                                const int* __restrict__ csr,
                                                u16* __restrict__ hout) {
    __shared__ __align__(16) u16 hT[RT * 128];
    __shared__ float asd[RB * 4];
    __shared__ float ev[GPB8][162];
    __shared__ float mS[GPB8][34], dS[GPB8][34];
    __shared__ float bvec[128];
    __shared__ float ws[3 * 128];
    __shared__ float w0a[12];
    __shared__ int srcS[Ee], dstS[Ee], offS[Nn_ + 1], eidS[Ee];
    const int t = threadIdx.x;
    const long bm = (long)blockIdx.x * RB;

    if (t < Ee) { srcS[t] = csr[t]; dstS[t] = csr[Ee + t]; eidS[t] = csr[180 + t]; }
    if (t >= 128 && t < 128 + Nn_ + 1) offS[t - 128] = csr[162 + t - 128];
    if (t < 128) bvec[t] = bias[t];
    for (int i = t; i < 384; i += 256) ws[i] = W0[i];
    if (t >= 200 && t < 212) {   // w0a from GLOBAL W0 (no dependency on ws staging)
        const int k = t - 200;
        const int ci = k >> 2, j = k & 3;
        const float* a = (j < 2) ? gas0 : gad0;
        const int hh = j & 1;
        float s = 0.f;
        for (int d = 0; d < HID; d++) s += W0[ci * 128 + hh * 64 + d] * a[hh * 64 + d];
        w0a[k] = s;
    }
    __syncthreads();

    // projection into swizzled LDS (2304 chunk-slots; pad rows zero)
    for (int i = t; i < RT * 16; i += 256) {
        const int r = i >> 4, cs = i & 15;
        union { uint4 qv; u16 s[8]; } pk;
        if (r < RB) {
            const long xr = (bm + r) * 3;
            const float x0 = x[xr], x1 = x[xr + 1], x2 = x[xr + 2];
            const int cg = cs ^ (r & 15);
#pragma unroll
            for (int j = 0; j < 8; j++) {
                const int c = cg * 8 + j;
                pk.s[j] = f2bf(x0 * ws[c] + x1 * ws[128 + c] + x2 * ws[256 + c]);
            }
            *(uint4*)&hT[(r * 16 + cs) * 8] = pk.qv;
        } else {
            *(uint4*)&hT[i * 8] = make_uint4(0, 0, 0, 0);
        }
    }
    // fp32 dots: 544 items
    for (int i = t; i < RB * 4; i += 256) {
        const int row = i >> 2, j = i & 3;
        const long xr = (bm + row) * 3;
        asd[i] = x[xr] * w0a[j] + x[xr + 1] * w0a[4 + j] + x[xr + 2] * w0a[8 + j];
    }
    gat_attn_lds(hT, asd, ev, mS, dS, bvec, srcS, dstS, offS, eidS, t, 1,
                 (u32*)hout + bm * 64);
}

// ---------------- bf16 MFMA GEMM: C[M,ldc] = A[M,K]bf16 @ Bt[N,K]bf16^T + b1[n]+b2[n] (fp32)
__global__ __launch_bounds__(256) void k_gemm_mfma(const u16* __restrict__ A,
                                                   const u16* __restrict__ Bt,
                                                   float* __restrict__ Cm,
                                                   const float* __restrict__ b1,
                                                   const float* __restrict__ b2,
                                                   int K, int ldc) {
    __shared__ u16 ldsA[128 * 64];
    __shared__ u16 ldsB[128 * 64];
    const int w = threadIdx.x >> 6;
    const int lane = threadIdx.x & 63;
    const long bm = (long)blockIdx.x * 128;
    const int bn = blockIdx.y * 128;
    const int wm = (w & 1) * 64, wn = (w >> 1) * 64;
    const int q = lane >> 4, col = lane & 15;
    f32x4 acc[4][4] = {};
    for (int k0 = 0; k0 < K; k0 += 64) {
#pragma unroll
        for (int i = 0; i < 4; i++) {
            const int slot = (w * 4 + i) * 64 + lane;
            const int r = slot >> 3, cs = slot & 7;
            const int cg = cs ^ (r & 7);
            async16(A + (bm + r) * (long)K + k0 + cg * 8, ldsA + (w * 4 + i) * 512);
            async16(Bt + (long)(bn + r) * K + k0 + cg * 8, ldsB + (w * 4 + i) * 512);
        }
        __syncthreads();
#pragma unroll
        for (int kk = 0; kk < 2; kk++) {
            bf16x8 af[4], bfr[4];
#pragma unroll
            for (int mt = 0; mt < 4; mt++) {
                const int m = wm + mt * 16 + col;
                const int cs = (kk * 4 + q) ^ (m & 7);
                af[mt] = *(const bf16x8*)&ldsA[m * 64 + cs * 8];
            }
#pragma unroll
            for (int nt = 0; nt < 4; nt++) {
                const int n = wn + nt * 16 + col;
                const int cs = (kk * 4 + q) ^ (n & 7);
                bfr[nt] = *(const bf16x8*)&ldsB[n * 64 + cs * 8];
            }
#pragma unroll
            for (int mt = 0; mt < 4; mt++)
#pragma unroll
                for (int nt = 0; nt < 4; nt++)
                    acc[mt][nt] = __builtin_amdgcn_mfma_f32_16x16x32_bf16(af[mt], bfr[nt], acc[mt][nt], 0, 0, 0);
        }
        __syncthreads();
    }
#pragma unroll
    for (int mt = 0; mt < 4; mt++)
#pragma unroll
        for (int nt = 0; nt < 4; nt++) {
            const int cg = bn + wn + nt * 16 + col;
            const float bb = b1[cg] + b2[cg];
#pragma unroll
            for (int r = 0; r < 4; r++) {
                const long rg = bm + wm + mt * 16 + q * 4 + r;
                Cm[rg * ldc + cg] = acc[mt][nt][r] + bb;
            }
        }
}

// ---------------- LSTM recurrence (r9 scalar: register whh + XW[t+1] prefetch)
// r10/r11 lesson: MFMA versions (156-166us) LOSE to this scalar (102us) -- the serial
// recurrence is latency-bound; MFMA's dependent chains + barriers at 5% occupancy cost
// more than the VALU MACs. Do not re-attempt without a step-time model showing <1600cyc.
template <int OBF16>
__global__ __launch_bounds__(512, 1) void k_lstm(const float* __restrict__ XW,
                                                 const float* __restrict__ whh,
                                                 void* __restrict__ hseq) {
    const int b = blockIdx.x, j = threadIdx.x;
    float4 w[32];
#pragma unroll
    for (int k = 0; k < 32; k++) w[k] = ((const float4*)(whh + (long)j * OUT_))[k];
    __shared__ __align__(16) float h_s[OUT_];
    __shared__ float c_s[OUT_];
    __shared__ float gate_s[G4];
    if (j < OUT_) { h_s[j] = 0.f; c_s[j] = 0.f; }
    float xw = XW[((long)b * Tt + 0) * G4 + j];
    __syncthreads();
    for (int t = 0; t < Tt; t++) {
        float xw_next = 0.f;
        if (t < Tt - 1) xw_next = XW[((long)b * Tt + t + 1) * G4 + j];
        float acc = xw;
#pragma unroll
        for (int k = 0; k < 32; k++) {
            float4 hv = ((const float4*)h_s)[k];
            acc += w[k].x * hv.x + w[k].y * hv.y + w[k].z * hv.z + w[k].w * hv.w;
        }
        gate_s[j] = acc;
        __syncthreads();
        if (j < OUT_) {
            float gi = gate_s[j], gf = gate_s[OUT_ + j], gg = gate_s[2 * OUT_ + j], go = gate_s[3 * OUT_ + j];
            float si = 1.f / (1.f + expf(-gi));
            float sf = 1.f / (1.f + expf(-gf));
            float so = 1.f / (1.f + expf(-go));
            float c = sf * c_s[j] + si * tanhf(gg);
            float hh = so * tanhf(c);
            c_s[j] = c;
            h_s[j] = hh;
            long idx = ((long)b * Tt + t) * OUT_ + j;
            if (OBF16) ((u16*)hseq)[idx] = f2bf(hh);
            else       ((float*)hseq)[idx] = hh;
        }
        xw = xw_next;
        __syncthreads();
    }
}

// ---------------- attention pooling + FC
__global__ __launch_bounds__(64) void k_attn_fc(const float* __restrict__ h2,
                                                const float* __restrict__ attn_w,
                                                const float* __restrict__ attn_b,
                                                const float* __restrict__ fc_w,
                                                const float* __restrict__ fc_b,
                                                float* __restrict__ out) {
    const int b = blockIdx.x, t = threadIdx.x;
    __shared__ float aw[Tt];
    __shared__ float ctx[OUT_];
    const float* hb = h2 + (long)b * Tt * OUT_;
    float acc = 0.f;
    for (int d = 0; d < OUT_; d++) acc += hb[t * OUT_ + d] * attn_w[d];
    float sc = tanhf(acc + attn_b[0]);
    float m = sc;
#pragma unroll
    for (int o = 32; o > 0; o >>= 1) m = fmaxf(m, __shfl_xor(m, o));
    float ex = expf(sc - m);
    float sum = ex;
#pragma unroll
    for (int o = 32; o > 0; o >>= 1) sum += __shfl_xor(sum, o);
    aw[t] = ex / sum;
    __syncthreads();
    for (int d = t; d < OUT_; d += 64) {
        float c = 0.f;
        for (int tt = 0; tt < Tt; tt++) c += aw[tt] * hb[tt * OUT_ + d];
        ctx[d] = c;
    }
    __syncthreads();
    if (t < NCLS) {
        float o = fc_b[t];
        for (int d = 0; d < OUT_; d++) o += ctx[d] * fc_w[t * OUT_ + d];
        out[b * NCLS + t] = o;
    }
}

extern "C" void kernel_launch(void* const* d_in, const int* in_sizes, int n_in,
                              void* d_out, int out_size, void* d_ws, size_t ws_size,
                              hipStream_t stream) {
    const float* x          = (const float*)d_in[0];
    const int*   edge_index = (const int*)d_in[1];
    const float* gw[4]  = {(const float*)d_in[2], (const float*)d_in[6], (const float*)d_in[10], (const float*)d_in[14]};
    const float* gas[4] = {(const float*)d_in[3], (const float*)d_in[7], (const float*)d_in[11], (const float*)d_in[15]};
    const float* gad[4] = {(const float*)d_in[4], (const float*)d_in[8], (const float*)d_in[12], (const float*)d_in[16]};
    const float* gb[4]  = {(const float*)d_in[5], (const float*)d_in[9], (const float*)d_in[13], (const float*)d_in[17]};
    const float* wih0 = (const float*)d_in[18];
    const float* whh0 = (const float*)d_in[19];
    const float* bih0 = (const float*)d_in[20];
    const float* bhh0 = (const float*)d_in[21];
    const float* wih1 = (const float*)d_in[22];
    const float* whh1 = (const float*)d_in[23];
    const float* bih1 = (const float*)d_in[24];
    const float* bhh1 = (const float*)d_in[25];
    const float* attn_w = (const float*)d_in[26];
    const float* attn_b = (const float*)d_in[27];
    const float* fc_w   = (const float*)d_in[28];
    const float* fc_b   = (const float*)d_in[29];
    float* out = (float*)d_out;
    char* p = (char*)d_ws;

    // Workspace (~153.6 MB; 176.2 MB proven OK in round 2)
    u16*   hbuf  = (u16*)(p + 0L);              // 71,303,168 B
    float* XW0   = (float*)(p + 71303168L);     // 33,554,432 B
    float* XW1   = (float*)(p + 104857600L);    // 33,554,432 B
    float* h2s   = (float*)(p + 138412032L);    //  8,388,608 B
    u16*   h1s   = (u16*)(p + 146800640L);      //  4,194,304 B
    u16*   wih0b = (u16*)(p + 150994944L);      //  2,228,224 B
    u16*   wih1b = (u16*)(p + 153223168L);      //    131,072 B
    u16*   wt1   = (u16*)(p + 153354240L);      //     32,768 B (x3)
    u16*   wt2   = (u16*)(p + 153387008L);
    u16*   wt3   = (u16*)(p + 153419776L);
    int*   csr   = (int*)(p + 153452544L);      //      1,044 B

    k_setup<<<1, 1, 0, stream>>>(edge_index, csr);
    k_convert_t128<<<64, 256, 0, stream>>>(gw[1], wt1);
    k_convert_t128<<<64, 256, 0, stream>>>(gw[2], wt2);
    k_convert_t128<<<64, 256, 0, stream>>>(gw[3], wt3);
    k_convert<<<(512 * 2176 + 255) / 256, 256, 0, stream>>>(wih0, wih0b, 512L * 2176);
    k_convert<<<256, 256, 0, stream>>>(wih1, wih1b, 512L * 128);

    // fused GAT layers: projection/GEMM + fp32 dots + attention, one kernel each
    k_l0attn<<<Mg / RB, 256, 0, stream>>>(x, gw[0], gas[0], gad[0], gb[0], csr, hbuf);
    k_gatfused<<<Mg / RB, 256, 0, stream>>>(hbuf, wt1, gas[1], gad[1], gb[1], csr, 0);
    k_gatfused<<<Mg / RB, 256, 0, stream>>>(hbuf, wt2, gas[2], gad[2], gb[2], csr, 1);
    k_gatfused<<<Mg / RB, 256, 0, stream>>>(hbuf, wt3, gas[3], gad[3], gb[3], csr, 0);

    // LSTM layer 0: input GEMM (hbuf == lstm_in [16384,2176] bf16) + scalar recurrence
    k_gemm_mfma<<<dim3(Gg / 128, 4), 256, 0, stream>>>(hbuf, wih0b, XW0, bih0, bhh0, LSTM_IN, G4);
    k_lstm<1><<<Bb, 512, 0, stream>>>(XW0, whh0, h1s);
    // LSTM layer 1
    k_gemm_mfma<<<dim3(Gg / 128, 4), 256, 0, stream>>>(h1s, wih1b, XW1, bih1, bhh1, OUT_, G4);
    k_lstm<0><<<Bb, 512, 0, stream>>>(XW1, whh1, h2s);

    k_attn_fc<<<Bb, 64, 0, stream>>>(h2s, attn_w, attn_b, fc_w, fc_b, out);
}

// Round 13
// 805.215 us; speedup vs baseline: 1.8240x; 1.8240x over previous
//
#include <hip/hip_runtime.h>
#include <hip/hip_bf16.h>

// Problem constants
#define Bb 256
#define Nn_ 17
#define CIN 3
#define HID 64
#define CCH 128        // HEADS*HID
#define Gg 16384       // B*S
#define Ee 81          // 64 edges + 17 self loops
#define LSTM_IN 2176   // 17*128
#define OUT_ 128
#define G4 512         // 4*OUT
#define NCLS 10
#define Tt 64
#define Mg (Gg * Nn_)  // 278528

typedef unsigned short u16;
typedef unsigned int u32;
typedef __attribute__((ext_vector_type(8))) short bf16x8;
typedef __attribute__((ext_vector_type(4))) float f32x4;

__device__ __forceinline__ u16 f2bf(float f) {   // RNE fp32->bf16
    u32 u = __float_as_uint(f);
    u += 0x7fffu + ((u >> 16) & 1u);
    return (u16)(u >> 16);
}
__device__ __forceinline__ float bflo(u32 v) { return __uint_as_float(v << 16); }
__device__ __forceinline__ float bfhi(u32 v) { return __uint_as_float(v & 0xffff0000u); }

__device__ __forceinline__ void async16(const void* g, void* l) {
    __builtin_amdgcn_global_load_lds((__attribute__((address_space(1))) u32*)g,
                                     (__attribute__((address_space(3))) u32*)l, 16, 0, 0);
}

// ---------------- setup: build src/dst + dst-CSR
__global__ void k_setup(const int* __restrict__ edge_index, int* __restrict__ csr) {
    if (threadIdx.x == 0 && blockIdx.x == 0) {
        int* src = csr;                    // [81]
        int* dst = csr + Ee;               // [81]
        int* off = csr + 2 * Ee;           // [18]
        int* eid = csr + 2 * Ee + Nn_ + 1; // [81]
        for (int e = 0; e < 64; e++) { src[e] = edge_index[e]; dst[e] = edge_index[64 + e]; }
        for (int n = 0; n < Nn_; n++) { src[64 + n] = n; dst[64 + n] = n; }
        int cnt[Nn_];
        for (int n = 0; n < Nn_; n++) cnt[n] = 0;
        for (int e = 0; e < Ee; e++) cnt[dst[e]]++;
        off[0] = 0;
        for (int n = 0; n < Nn_; n++) off[n + 1] = off[n] + cnt[n];
        int pos[Nn_];
        for (int n = 0; n < Nn_; n++) pos[n] = off[n];
        for (int e = 0; e < Ee; e++) eid[pos[dst[e]]++] = e;
    }
}

__global__ void k_convert(const float* __restrict__ in, u16* __restrict__ out, long n) {
    long i = (long)blockIdx.x * 256 + threadIdx.x;
    if (i < n) out[i] = f2bf(in[i]);
}
// 128x128 weight: [k][n] -> bf16 [n][k] (transpose for MFMA B-operand)
__global__ void k_convert_t128(const float* __restrict__ in, u16* __restrict__ out) {
    int i = blockIdx.x * 256 + threadIdx.x;  // over 16384
    int n = i >> 7, k = i & 127;
    out[i] = f2bf(in[k * 128 + n]);
}

// ---------------- GAT layer 0: h[Mg,128]=x@W0 (bf16) + aux[Mg,4]=x@(W0@a) (fp32)
__global__ __launch_bounds__(256) void k_l0(const float* __restrict__ x,
                                            const float* __restrict__ W0,
                                            const float* __restrict__ gas0,
                                            const float* __restrict__ gad0,
                                            u16* __restrict__ h, float* __restrict__ aux) {
    __shared__ float ws[3 * 128];
    __shared__ float w0a[12];   // [ci][j]  j: src_h0,src_h1,dst_h0,dst_h1
    const int t = threadIdx.x;
    for (int i = t; i < 384; i += 256) ws[i] = W0[i];
    __syncthreads();
    if (t < 12) {
        int ci = t >> 2, j = t & 3;
        const float* a = (j < 2) ? gas0 : gad0;
        int hh = j & 1;
        float s = 0.f;
        for (int d = 0; d < HID; d++) s += ws[ci * 128 + hh * 64 + d] * a[hh * 64 + d];
        w0a[t] = s;
    }
    __syncthreads();
    const long row = (long)blockIdx.x * 16 + (t >> 4);
    const int c0 = (t & 15) * 8;
    const float x0 = x[row * 3 + 0], x1 = x[row * 3 + 1], x2 = x[row * 3 + 2];
    union { uint4 u; u16 s[8]; } o;
#pragma unroll
    for (int j = 0; j < 8; j++)
        o.s[j] = f2bf(x0 * ws[c0 + j] + x1 * ws[128 + c0 + j] + x2 * ws[256 + c0 + j]);
    *(uint4*)(h + row * 128 + c0) = o.u;
    if ((t & 15) < 4) {
        int j = t & 3;
        aux[row * 4 + j] = x0 * w0a[j] + x1 * w0a[4 + j] + x2 * w0a[8 + j];
    }
}

// ---------------- GAT MFMA GEMM (in-place): hbuf = hbuf @ W ; aux = fp32 dots vs a_src/a_dst
__global__ __launch_bounds__(256) void k_gemm_gat(u16* __restrict__ HB,
                                                  const u16* __restrict__ Wt,
                                                  const float* __restrict__ a_src,
                                                  const float* __restrict__ a_dst,
                                                  float* __restrict__ aux) {
    __shared__ u16 ldsA[128 * 128];  // 32 KB
    __shared__ float avec[128], dvec[128];
    const int t = threadIdx.x;
    const int w = t >> 6, lane = t & 63;
    const int q = lane >> 4, col = lane & 15;
    const long bm = (long)blockIdx.x * 128;
    const int wm = w * 32;

    if (t < 128) avec[t] = a_src[t];
    else dvec[t - 128] = a_dst[t - 128];

#pragma unroll
    for (int i = 0; i < 8; i++) {
        const int slot = (w * 8 + i) * 64 + lane;
        const int r = slot >> 4, cs = slot & 15;
        const int cg = cs ^ (r & 15);
        async16(HB + (bm + r) * 128 + cg * 8, ldsA + (w * 8 + i) * 512);
    }
    __syncthreads();

    f32x4 acc[2][8] = {};
#pragma unroll
    for (int ks = 0; ks < 4; ks++) {
        const int ck = ks * 4 + q;
        bf16x8 af[2];
#pragma unroll
        for (int mt = 0; mt < 2; mt++) {
            const int m = wm + mt * 16 + col;
            af[mt] = *(const bf16x8*)&ldsA[m * 128 + ((ck ^ (m & 15)) << 3)];
        }
#pragma unroll
        for (int nt = 0; nt < 8; nt++) {
            bf16x8 bf = *(const bf16x8*)&Wt[(nt * 16 + col) * 128 + ck * 8];
            acc[0][nt] = __builtin_amdgcn_mfma_f32_16x16x32_bf16(af[0], bf, acc[0][nt], 0, 0, 0);
            acc[1][nt] = __builtin_amdgcn_mfma_f32_16x16x32_bf16(af[1], bf, acc[1][nt], 0, 0, 0);
        }
    }
    __syncthreads();
#pragma unroll
    for (int mt = 0; mt < 2; mt++) {
#pragma unroll
        for (int nt = 0; nt < 8; nt++) {
            const int cg = nt * 16 + col;
#pragma unroll
            for (int r = 0; r < 4; r++) {
                const long rg = bm + wm + mt * 16 + q * 4 + r;
                HB[rg * 128 + cg] = f2bf(acc[mt][nt][r]);
            }
        }
#pragma unroll
        for (int r = 0; r < 4; r++) {
            float s0 = 0.f, s1 = 0.f, d0 = 0.f, d1 = 0.f;
#pragma unroll
            for (int nt = 0; nt < 4; nt++) {
                const float v = acc[mt][nt][r];
                s0 += v * avec[nt * 16 + col];
                d0 += v * dvec[nt * 16 + col];
            }
#pragma unroll
            for (int nt = 4; nt < 8; nt++) {
                const float v = acc[mt][nt][r];
                s1 += v * avec[nt * 16 + col];
                d1 += v * dvec[nt * 16 + col];
            }
#pragma unroll
            for (int o = 1; o < 16; o <<= 1) {
                s0 += __shfl_xor(s0, o);
                s1 += __shfl_xor(s1, o);
                d0 += __shfl_xor(d0, o);
                d1 += __shfl_xor(d1, o);
            }
            if (col == 0) {
                const long rg = bm + wm + mt * 16 + q * 4 + r;
                aux[rg * 4 + 0] = s0;
                aux[rg * 4 + 1] = s1;
                aux[rg * 4 + 2] = d0;
                aux[rg * 4 + 3] = d1;
            }
        }
    }
}

// ---------------- GAT attention (4 graphs/block)
#define GPB 4
__global__ __launch_bounds__(256) void k_gat_attn(u16* __restrict__ h,
                                                  const float* __restrict__ aux,
                                                  const float* __restrict__ bias,
                                                  const int* __restrict__ csr,
                                                  int relu_flag) {
    __shared__ u32 hs[GPB * Nn_ * 64];
    __shared__ float asd[GPB * Nn_ * 4];     // 272 entries
    __shared__ float ev[GPB][162];
    __shared__ float mS[GPB][34], dS[GPB][34];
    __shared__ float bvec[128];
    __shared__ int srcS[Ee], dstS[Ee], offS[Nn_ + 1], eidS[Ee];
    const int t = threadIdx.x;
    const long g0 = (long)blockIdx.x * GPB;

    if (t < Ee) { srcS[t] = csr[t]; dstS[t] = csr[Ee + t]; eidS[t] = csr[180 + t]; }
    if (t >= 128 && t < 128 + Nn_ + 1) offS[t - 128] = csr[162 + t - 128];
    if (t < 128) bvec[t] = bias[t];
    {
        const u32* hg = (const u32*)h + g0 * 1088;
#pragma unroll
        for (int it = 0; it < 17; it++) hs[t + it * 256] = hg[t + it * 256];
        const float* ag = aux + g0 * 68;
        // 272 entries > 256 threads: full coverage loop (r8 bugfix)
        for (int i = t; i < GPB * Nn_ * 4; i += 256) asd[i] = ag[i];
    }
    __syncthreads();
    for (int i = t; i < GPB * 162; i += 256) {
        const int g = i / 162, rem = i % 162, e = rem >> 1, hh = rem & 1;
        float v = asd[(g * Nn_ + srcS[e]) * 4 + hh] + asd[(g * Nn_ + dstS[e]) * 4 + 2 + hh];
        ev[g][rem] = (v > 0.f) ? v : 0.2f * v;
    }
    __syncthreads();
    if (t < GPB * 34) {
        const int g = t / 34, rem = t % 34, n = rem >> 1, hh = rem & 1;
        const int p0 = offS[n], p1 = offS[n + 1];
        float m = -1e30f;
        for (int p = p0; p < p1; p++) m = fmaxf(m, ev[g][eidS[p] * 2 + hh]);
        float den = 0.f;
        for (int p = p0; p < p1; p++) den += expf(ev[g][eidS[p] * 2 + hh] - m);
        mS[g][rem] = m;
        dS[g][rem] = den;
    }
    __syncthreads();
    for (int i = t; i < GPB * 162; i += 256) {
        const int g = i / 162, rem = i % 162, e = rem >> 1, hh = rem & 1;
        const int n = dstS[e];
        ev[g][rem] = expf(ev[g][rem] - mS[g][n * 2 + hh]) / (dS[g][n * 2 + hh] + 1e-16f);
    }
    __syncthreads();
    u32* hg = (u32*)h + g0 * 1088;
#pragma unroll
    for (int it = 0; it < 17; it++) {
        const int i = t + it * 256;
        const int gg = i / 1088, rr = i % 1088;
        const int n = rr >> 6, cp = rr & 63, hh = cp >> 5;
        const int p0 = offS[n], p1 = offS[n + 1];
        float a0 = 0.f, a1 = 0.f;
        for (int p = p0; p < p1; p++) {
            const int e = eidS[p];
            const u32 hv = hs[(gg * Nn_ + srcS[e]) * 64 + cp];
            const float al = ev[gg][e * 2 + hh];
            a0 += al * bflo(hv);
            a1 += al * bfhi(hv);
        }
        a0 += bvec[cp * 2];
        a1 += bvec[cp * 2 + 1];
        if (relu_flag) { a0 = fmaxf(a0, 0.f); a1 = fmaxf(a1, 0.f); }
        hg[gg * 1088 + n * 64 + cp] = (u32)f2bf(a0) | ((u32)f2bf(a1) << 16);
    }
}

// ---------------- bf16 MFMA GEMM: C[M,ldc] = A[M,K]bf16 @ Bt[N,K]bf16^T + b1[n]+b2[n] (fp32)
__global__ __launch_bounds__(256) void k_gemm_mfma(const u16* __restrict__ A,
                                                   const u16* __restrict__ Bt,
                                                   float* __restrict__ Cm,
                                                   const float* __restrict__ b1,
                                                   const float* __restrict__ b2,
                                                   int K, int ldc) {
    __shared__ u16 ldsA[128 * 64];
    __shared__ u16 ldsB[128 * 64];
    const int w = threadIdx.x >> 6;
    const int lane = threadIdx.x & 63;
    const long bm = (long)blockIdx.x * 128;
    const int bn = blockIdx.y * 128;
    const int wm = (w & 1) * 64, wn = (w >> 1) * 64;
    const int q = lane >> 4, col = lane & 15;
    f32x4 acc[4][4] = {};
    for (int k0 = 0; k0 < K; k0 += 64) {
#pragma unroll
        for (int i = 0; i < 4; i++) {
            const int slot = (w * 4 + i) * 64 + lane;
            const int r = slot >> 3, cs = slot & 7;
            const int cg = cs ^ (r & 7);
            async16(A + (bm + r) * (long)K + k0 + cg * 8, ldsA + (w * 4 + i) * 512);
            async16(Bt + (long)(bn + r) * K + k0 + cg * 8, ldsB + (w * 4 + i) * 512);
        }
        __syncthreads();
#pragma unroll
        for (int kk = 0; kk < 2; kk++) {
            bf16x8 af[4], bfr[4];
#pragma unroll
            for (int mt = 0; mt < 4; mt++) {
                const int m = wm + mt * 16 + col;
                const int cs = (kk * 4 + q) ^ (m & 7);
                af[mt] = *(const bf16x8*)&ldsA[m * 64 + cs * 8];
            }
#pragma unroll
            for (int nt = 0; nt < 4; nt++) {
                const int n = wn + nt * 16 + col;
                const int cs = (kk * 4 + q) ^ (n & 7);
                bfr[nt] = *(const bf16x8*)&ldsB[n * 64 + cs * 8];
            }
#pragma unroll
            for (int mt = 0; mt < 4; mt++)
#pragma unroll
                for (int nt = 0; nt < 4; nt++)
                    acc[mt][nt] = __builtin_amdgcn_mfma_f32_16x16x32_bf16(af[mt], bfr[nt], acc[mt][nt], 0, 0, 0);
        }
        __syncthreads();
    }
#pragma unroll
    for (int mt = 0; mt < 4; mt++)
#pragma unroll
        for (int nt = 0; nt < 4; nt++) {
            const int cg = bn + wn + nt * 16 + col;
            const float bb = b1[cg] + b2[cg];
#pragma unroll
            for (int r = 0; r < 4; r++) {
                const long rg = bm + wm + mt * 16 + q * 4 + r;
                Cm[rg * ldc + cg] = acc[mt][nt][r] + bb;
            }
        }
}

// ---------------- LSTM recurrence: whh bf16 packed in 64 u32 registers
// r9 PMC: VGPR_Count=80 proved float4 w[32] (128 VGPRs) was NOT register-resident ->
// whh re-fetched from L2 every step: 256 CU x 64 steps x 256 KB / 34.5 TB/s ~= 122us,
// matching the measured 102us (L2-BW bound). bf16-packed whh needs only 64 VGPRs ->
// register-resident (or at worst halves L2 bytes). h/c/gates stay fp32 (strictly more
// accurate than r10/r11's passing whh-bf16+h-bf16 variant). XW[t+1] register prefetch kept.
template <int OBF16>
__global__ __launch_bounds__(512, 1) void k_lstm(const float* __restrict__ XW,
                                                 const u16* __restrict__ whhb,
                                                 void* __restrict__ hseq) {
    const int b = blockIdx.x, j = threadIdx.x;
    u32 wp[64];   // 128 bf16 = 64 VGPRs
    const u32* wrow = (const u32*)(whhb + (long)j * OUT_);
#pragma unroll
    for (int k = 0; k < 64; k++) wp[k] = wrow[k];
    __shared__ __align__(16) float h_s[OUT_];
    __shared__ float c_s[OUT_];
    __shared__ float gate_s[G4];
    if (j < OUT_) { h_s[j] = 0.f; c_s[j] = 0.f; }
    float xw = XW[((long)b * Tt + 0) * G4 + j];
    __syncthreads();
    for (int t = 0; t < Tt; t++) {
        float xw_next = 0.f;
        if (t < Tt - 1) xw_next = XW[((long)b * Tt + t + 1) * G4 + j];
        float acc = xw;
#pragma unroll
        for (int k = 0; k < 32; k++) {
            float4 hv = ((const float4*)h_s)[k];
            const u32 p0 = wp[2 * k], p1 = wp[2 * k + 1];
            acc += bflo(p0) * hv.x + bfhi(p0) * hv.y + bflo(p1) * hv.z + bfhi(p1) * hv.w;
        }
        gate_s[j] = acc;
        __syncthreads();
        if (j < OUT_) {
            float gi = gate_s[j], gf = gate_s[OUT_ + j], gg = gate_s[2 * OUT_ + j], go = gate_s[3 * OUT_ + j];
            float si = 1.f / (1.f + expf(-gi));
            float sf = 1.f / (1.f + expf(-gf));
            float so = 1.f / (1.f + expf(-go));
            float c = sf * c_s[j] + si * tanhf(gg);
            float hh = so * tanhf(c);
            c_s[j] = c;
            h_s[j] = hh;
            long idx = ((long)b * Tt + t) * OUT_ + j;
            if (OBF16) ((u16*)hseq)[idx] = f2bf(hh);
            else       ((float*)hseq)[idx] = hh;
        }
        xw = xw_next;
        __syncthreads();
    }
}

// ---------------- attention pooling + FC
__global__ __launch_bounds__(64) void k_attn_fc(const float* __restrict__ h2,
                                                const float* __restrict__ attn_w,
                                                const float* __restrict__ attn_b,
                                                const float* __restrict__ fc_w,
                                                const float* __restrict__ fc_b,
                                                float* __restrict__ out) {
    const int b = blockIdx.x, t = threadIdx.x;
    __shared__ float aw[Tt];
    __shared__ float ctx[OUT_];
    const float* hb = h2 + (long)b * Tt * OUT_;
    float acc = 0.f;
    for (int d = 0; d < OUT_; d++) acc += hb[t * OUT_ + d] * attn_w[d];
    float sc = tanhf(acc + attn_b[0]);
    float m = sc;
#pragma unroll
    for (int o = 32; o > 0; o >>= 1) m = fmaxf(m, __shfl_xor(m, o));
    float ex = expf(sc - m);
    float sum = ex;
#pragma unroll
    for (int o = 32; o > 0; o >>= 1) sum += __shfl_xor(sum, o);
    aw[t] = ex / sum;
    __syncthreads();
    for (int d = t; d < OUT_; d += 64) {
        float c = 0.f;
        for (int tt = 0; tt < Tt; tt++) c += aw[tt] * hb[tt * OUT_ + d];
        ctx[d] = c;
    }
    __syncthreads();
    if (t < NCLS) {
        float o = fc_b[t];
        for (int d = 0; d < OUT_; d++) o += ctx[d] * fc_w[t * OUT_ + d];
        out[b * NCLS + t] = o;
    }
}

extern "C" void kernel_launch(void* const* d_in, const int* in_sizes, int n_in,
                              void* d_out, int out_size, void* d_ws, size_t ws_size,
                              hipStream_t stream) {
    const float* x          = (const float*)d_in[0];
    const int*   edge_index = (const int*)d_in[1];
    const float* gw[4]  = {(const float*)d_in[2], (const float*)d_in[6], (const float*)d_in[10], (const float*)d_in[14]};
    const float* gas[4] = {(const float*)d_in[3], (const float*)d_in[7], (const float*)d_in[11], (const float*)d_in[15]};
    const float* gad[4] = {(const float*)d_in[4], (const float*)d_in[8], (const float*)d_in[12], (const float*)d_in[16]};
    const float* gb[4]  = {(const float*)d_in[5], (const float*)d_in[9], (const float*)d_in[13], (const float*)d_in[17]};
    const float* wih0 = (const float*)d_in[18];
    const float* whh0 = (const float*)d_in[19];
    const float* bih0 = (const float*)d_in[20];
    const float* bhh0 = (const float*)d_in[21];
    const float* wih1 = (const float*)d_in[22];
    const float* whh1 = (const float*)d_in[23];
    const float* bih1 = (const float*)d_in[24];
    const float* bhh1 = (const float*)d_in[25];
    const float* attn_w = (const float*)d_in[26];
    const float* attn_b = (const float*)d_in[27];
    const float* fc_w   = (const float*)d_in[28];
    const float* fc_b   = (const float*)d_in[29];
    float* out = (float*)d_out;
    char* p = (char*)d_ws;

    // Workspace (~158.2 MB; 176.2 MB proven OK in round 2)
    u16*   hbuf  = (u16*)(p + 0L);              // 71,303,168 B
    float* aux   = (float*)(p + 71303168L);     //  4,456,448 B
    float* XW0   = (float*)(p + 75759616L);     // 33,554,432 B
    float* XW1   = (float*)(p + 109314048L);    // 33,554,432 B
    float* h2s   = (float*)(p + 142868480L);    //  8,388,608 B
    u16*   h1s   = (u16*)(p + 151257088L);      //  4,194,304 B
    u16*   wih0b = (u16*)(p + 155451392L);      //  2,228,224 B
    u16*   wih1b = (u16*)(p + 157679616L);      //    131,072 B
    u16*   whh0b = (u16*)(p + 157810688L);      //    131,072 B
    u16*   whh1b = (u16*)(p + 157941760L);      //    131,072 B
    u16*   wt1   = (u16*)(p + 158072832L);      //     32,768 B (x3)
    u16*   wt2   = (u16*)(p + 158105600L);
    u16*   wt3   = (u16*)(p + 158138368L);
    int*   csr   = (int*)(p + 158171136L);      //      1,044 B

    k_setup<<<1, 1, 0, stream>>>(edge_index, csr);
    k_convert_t128<<<64, 256, 0, stream>>>(gw[1], wt1);
    k_convert_t128<<<64, 256, 0, stream>>>(gw[2], wt2);
    k_convert_t128<<<64, 256, 0, stream>>>(gw[3], wt3);
    k_convert<<<(512 * 2176 + 255) / 256, 256, 0, stream>>>(wih0, wih0b, 512L * 2176);
    k_convert<<<256, 256, 0, stream>>>(wih1, wih1b, 512L * 128);
    k_convert<<<256, 256, 0, stream>>>(whh0, whh0b, 512L * 128);
    k_convert<<<256, 256, 0, stream>>>(whh1, whh1b, 512L * 128);

    // GAT layer 0 projection (+fp32 attn dots) then attention
    k_l0<<<Mg / 16, 256, 0, stream>>>(x, gw[0], gas[0], gad[0], hbuf, aux);
    k_gat_attn<<<Gg / GPB, 256, 0, stream>>>(hbuf, aux, gb[0], csr, 1);
    // layers 1..3: in-place MFMA GEMM with fp32 dot epilogue, then attention
    k_gemm_gat<<<Mg / 128, 256, 0, stream>>>(hbuf, wt1, gas[1], gad[1], aux);
    k_gat_attn<<<Gg / GPB, 256, 0, stream>>>(hbuf, aux, gb[1], csr, 0);
    k_gemm_gat<<<Mg / 128, 256, 0, stream>>>(hbuf, wt2, gas[2], gad[2], aux);
    k_gat_attn<<<Gg / GPB, 256, 0, stream>>>(hbuf, aux, gb[2], csr, 1);
    k_gemm_gat<<<Mg / 128, 256, 0, stream>>>(hbuf, wt3, gas[3], gad[3], aux);
    k_gat_attn<<<Gg / GPB, 256, 0, stream>>>(hbuf, aux, gb[3], csr, 0);

    // LSTM layer 0: input GEMM (hbuf == lstm_in [16384,2176] bf16) + recurrence
    k_gemm_mfma<<<dim3(Gg / 128, 4), 256, 0, stream>>>(hbuf, wih0b, XW0, bih0, bhh0, LSTM_IN, G4);
    k_lstm<1><<<Bb, 512, 0, stream>>>(XW0, whh0b, h1s);
    // LSTM layer 1
    k_gemm_mfma<<<dim3(Gg / 128, 4), 256, 0, stream>>>(h1s, wih1b, XW1, bih1, bhh1, OUT_, G4);
    k_lstm<0><<<Bb, 512, 0, stream>>>(XW1, whh1b, h2s);

    k_attn_fc<<<Bb, 64, 0, stream>>>(h2s, attn_w, attn_b, fc_w, fc_b, out);
}

// Round 14
// 733.166 us; speedup vs baseline: 2.0033x; 1.0983x over previous
//
#include <hip/hip_runtime.h>
#include <hip/hip_bf16.h>

// Problem constants
#define Bb 256
#define Nn_ 17
#define CIN 3
#define HID 64
#define CCH 128        // HEADS*HID
#define Gg 16384       // B*S
#define Ee 81          // 64 edges + 17 self loops
#define LSTM_IN 2176   // 17*128
#define OUT_ 128
#define G4 512         // 4*OUT
#define NCLS 10
#define Tt 64
#define Mg (Gg * Nn_)  // 278528

typedef unsigned short u16;
typedef unsigned int u32;
typedef __attribute__((ext_vector_type(8))) short bf16x8;
typedef __attribute__((ext_vector_type(4))) float f32x4;

__device__ __forceinline__ u16 f2bf(float f) {   // RNE fp32->bf16
    u32 u = __float_as_uint(f);
    u += 0x7fffu + ((u >> 16) & 1u);
    return (u16)(u >> 16);
}
__device__ __forceinline__ float bflo(u32 v) { return __uint_as_float(v << 16); }
__device__ __forceinline__ float bfhi(u32 v) { return __uint_as_float(v & 0xffff0000u); }

__device__ __forceinline__ void async16(const void* g, void* l) {
    __builtin_amdgcn_global_load_lds((__attribute__((address_space(1))) u32*)g,
                                     (__attribute__((address_space(3))) u32*)l, 16, 0, 0);
}

// ---------------- setup: build src/dst + dst-CSR
__global__ void k_setup(const int* __restrict__ edge_index, int* __restrict__ csr) {
    if (threadIdx.x == 0 && blockIdx.x == 0) {
        int* src = csr;                    // [81]
        int* dst = csr + Ee;               // [81]
        int* off = csr + 2 * Ee;           // [18]
        int* eid = csr + 2 * Ee + Nn_ + 1; // [81]
        for (int e = 0; e < 64; e++) { src[e] = edge_index[e]; dst[e] = edge_index[64 + e]; }
        for (int n = 0; n < Nn_; n++) { src[64 + n] = n; dst[64 + n] = n; }
        int cnt[Nn_];
        for (int n = 0; n < Nn_; n++) cnt[n] = 0;
        for (int e = 0; e < Ee; e++) cnt[dst[e]]++;
        off[0] = 0;
        for (int n = 0; n < Nn_; n++) off[n + 1] = off[n] + cnt[n];
        int pos[Nn_];
        for (int n = 0; n < Nn_; n++) pos[n] = off[n];
        for (int e = 0; e < Ee; e++) eid[pos[dst[e]]++] = e;
    }
}

__global__ void k_convert(const float* __restrict__ in, u16* __restrict__ out, long n) {
    long i = (long)blockIdx.x * 256 + threadIdx.x;
    if (i < n) out[i] = f2bf(in[i]);
}
// 128x128 weight: [k][n] -> bf16 [n][k] (transpose for MFMA B-operand)
__global__ void k_convert_t128(const float* __restrict__ in, u16* __restrict__ out) {
    int i = blockIdx.x * 256 + threadIdx.x;  // over 16384
    int n = i >> 7, k = i & 127;
    out[i] = f2bf(in[k * 128 + n]);
}

// ---------------- GAT layer 0: h[Mg,128]=x@W0 (bf16) + aux[Mg,4]=x@(W0@a) (fp32)
__global__ __launch_bounds__(256) void k_l0(const float* __restrict__ x,
                                            const float* __restrict__ W0,
                                            const float* __restrict__ gas0,
                                            const float* __restrict__ gad0,
                                            u16* __restrict__ h, float* __restrict__ aux) {
    __shared__ float ws[3 * 128];
    __shared__ float w0a[12];   // [ci][j]  j: src_h0,src_h1,dst_h0,dst_h1
    const int t = threadIdx.x;
    for (int i = t; i < 384; i += 256) ws[i] = W0[i];
    __syncthreads();
    if (t < 12) {
        int ci = t >> 2, j = t & 3;
        const float* a = (j < 2) ? gas0 : gad0;
        int hh = j & 1;
        float s = 0.f;
        for (int d = 0; d < HID; d++) s += ws[ci * 128 + hh * 64 + d] * a[hh * 64 + d];
        w0a[t] = s;
    }
    __syncthreads();
    const long row = (long)blockIdx.x * 16 + (t >> 4);
    const int c0 = (t & 15) * 8;
    const float x0 = x[row * 3 + 0], x1 = x[row * 3 + 1], x2 = x[row * 3 + 2];
    union { uint4 u; u16 s[8]; } o;
#pragma unroll
    for (int j = 0; j < 8; j++)
        o.s[j] = f2bf(x0 * ws[c0 + j] + x1 * ws[128 + c0 + j] + x2 * ws[256 + c0 + j]);
    *(uint4*)(h + row * 128 + c0) = o.u;
    if ((t & 15) < 4) {
        int j = t & 3;
        aux[row * 4 + j] = x0 * w0a[j] + x1 * w0a[4 + j] + x2 * w0a[8 + j];
    }
}

// ---------------- GAT MFMA GEMM (in-place): hbuf = hbuf @ W ; aux = fp32 dots vs a_src/a_dst
__global__ __launch_bounds__(256) void k_gemm_gat(u16* __restrict__ HB,
                                                  const u16* __restrict__ Wt,
                                                  const float* __restrict__ a_src,
                                                  const float* __restrict__ a_dst,
                                                  float* __restrict__ aux) {
    __shared__ u16 ldsA[128 * 128];  // 32 KB
    __shared__ float avec[128], dvec[128];
    const int t = threadIdx.x;
    const int w = t >> 6, lane = t & 63;
    const int q = lane >> 4, col = lane & 15;
    const long bm = (long)blockIdx.x * 128;
    const int wm = w * 32;

    if (t < 128) avec[t] = a_src[t];
    else dvec[t - 128] = a_dst[t - 128];

#pragma unroll
    for (int i = 0; i < 8; i++) {
        const int slot = (w * 8 + i) * 64 + lane;
        const int r = slot >> 4, cs = slot & 15;
        const int cg = cs ^ (r & 15);
        async16(HB + (bm + r) * 128 + cg * 8, ldsA + (w * 8 + i) * 512);
    }
    __syncthreads();

    f32x4 acc[2][8] = {};
#pragma unroll
    for (int ks = 0; ks < 4; ks++) {
        const int ck = ks * 4 + q;
        bf16x8 af[2];
#pragma unroll
        for (int mt = 0; mt < 2; mt++) {
            const int m = wm + mt * 16 + col;
            af[mt] = *(const bf16x8*)&ldsA[m * 128 + ((ck ^ (m & 15)) << 3)];
        }
#pragma unroll
        for (int nt = 0; nt < 8; nt++) {
            bf16x8 bf = *(const bf16x8*)&Wt[(nt * 16 + col) * 128 + ck * 8];
            acc[0][nt] = __builtin_amdgcn_mfma_f32_16x16x32_bf16(af[0], bf, acc[0][nt], 0, 0, 0);
            acc[1][nt] = __builtin_amdgcn_mfma_f32_16x16x32_bf16(af[1], bf, acc[1][nt], 0, 0, 0);
        }
    }
    __syncthreads();
#pragma unroll
    for (int mt = 0; mt < 2; mt++) {
#pragma unroll
        for (int nt = 0; nt < 8; nt++) {
            const int cg = nt * 16 + col;
#pragma unroll
            for (int r = 0; r < 4; r++) {
                const long rg = bm + wm + mt * 16 + q * 4 + r;
                HB[rg * 128 + cg] = f2bf(acc[mt][nt][r]);
            }
        }
#pragma unroll
        for (int r = 0; r < 4; r++) {
            float s0 = 0.f, s1 = 0.f, d0 = 0.f, d1 = 0.f;
#pragma unroll
            for (int nt = 0; nt < 4; nt++) {
                const float v = acc[mt][nt][r];
                s0 += v * avec[nt * 16 + col];
                d0 += v * dvec[nt * 16 + col];
            }
#pragma unroll
            for (int nt = 4; nt < 8; nt++) {
                const float v = acc[mt][nt][r];
                s1 += v * avec[nt * 16 + col];
                d1 += v * dvec[nt * 16 + col];
            }
#pragma unroll
            for (int o = 1; o < 16; o <<= 1) {
                s0 += __shfl_xor(s0, o);
                s1 += __shfl_xor(s1, o);
                d0 += __shfl_xor(d0, o);
                d1 += __shfl_xor(d1, o);
            }
            if (col == 0) {
                const long rg = bm + wm + mt * 16 + q * 4 + r;
                aux[rg * 4 + 0] = s0;
                aux[rg * 4 + 1] = s1;
                aux[rg * 4 + 2] = d0;
                aux[rg * 4 + 3] = d1;
            }
        }
    }
}

// ---------------- GAT attention (4 graphs/block), 16B-vectorized staging + aggregation
#define GPB 4
__global__ __launch_bounds__(256) void k_gat_attn(u16* __restrict__ h,
                                                  const float* __restrict__ aux,
                                                  const float* __restrict__ bias,
                                                  const int* __restrict__ csr,
                                                  int relu_flag) {
    __shared__ __align__(16) u32 hs[GPB * Nn_ * 64];   // [g][n][cp]
    __shared__ float asd[GPB * Nn_ * 4];
    __shared__ float ev[GPB][162];
    __shared__ float mS[GPB][34], dS[GPB][34];
    __shared__ float bvec[128];
    __shared__ int srcS[Ee], dstS[Ee], offS[Nn_ + 1], eidS[Ee];
    const int t = threadIdx.x;
    const long g0 = (long)blockIdx.x * GPB;

    if (t < Ee) { srcS[t] = csr[t]; dstS[t] = csr[Ee + t]; eidS[t] = csr[180 + t]; }
    if (t >= 128 && t < 128 + Nn_ + 1) offS[t - 128] = csr[162 + t - 128];
    if (t < 128) bvec[t] = bias[t];
    {
        const uint4* hg4 = (const uint4*)((const u32*)h + g0 * 1088);
        for (int i = t; i < GPB * Nn_ * 16; i += 256) ((uint4*)hs)[i] = hg4[i];
        const float* ag = aux + g0 * 68;
        for (int i = t; i < GPB * Nn_ * 4; i += 256) asd[i] = ag[i];   // 272 > 256 (r8 bugfix)
    }
    __syncthreads();
    for (int i = t; i < GPB * 162; i += 256) {
        const int g = i / 162, rem = i % 162, e = rem >> 1, hh = rem & 1;
        float v = asd[(g * Nn_ + srcS[e]) * 4 + hh] + asd[(g * Nn_ + dstS[e]) * 4 + 2 + hh];
        ev[g][rem] = (v > 0.f) ? v : 0.2f * v;
    }
    __syncthreads();
    if (t < GPB * 34) {
        const int g = t / 34, rem = t % 34, n = rem >> 1, hh = rem & 1;
        const int p0 = offS[n], p1 = offS[n + 1];
        float m = -1e30f;
        for (int p = p0; p < p1; p++) m = fmaxf(m, ev[g][eidS[p] * 2 + hh]);
        float den = 0.f;
        for (int p = p0; p < p1; p++) den += expf(ev[g][eidS[p] * 2 + hh] - m);
        mS[g][rem] = m;
        dS[g][rem] = den;
    }
    __syncthreads();
    for (int i = t; i < GPB * 162; i += 256) {
        const int g = i / 162, rem = i % 162, e = rem >> 1, hh = rem & 1;
        const int n = dstS[e];
        ev[g][rem] = expf(ev[g][rem] - mS[g][n * 2 + hh]) / (dS[g][n * 2 + hh] + 1e-16f);
    }
    __syncthreads();
    // aggregation: 1088 items = (g, n, cq), each covers 8 bf16 columns (one uint4)
    uint4* hgo4 = (uint4*)((u32*)h + g0 * 1088);
    for (int i = t; i < GPB * Nn_ * 16; i += 256) {
        const int g = i / (Nn_ * 16), rem = i % (Nn_ * 16);
        const int n = rem >> 4, cq = rem & 15, hh = cq >> 3;
        const int p0 = offS[n], p1 = offS[n + 1];
        float a[8] = {};
        for (int p = p0; p < p1; p++) {
            const int e = eidS[p];
            const uint4 hv = ((const uint4*)hs)[(g * Nn_ + srcS[e]) * 16 + cq];
            const float al = ev[g][e * 2 + hh];
            a[0] += al * bflo(hv.x); a[1] += al * bfhi(hv.x);
            a[2] += al * bflo(hv.y); a[3] += al * bfhi(hv.y);
            a[4] += al * bflo(hv.z); a[5] += al * bfhi(hv.z);
            a[6] += al * bflo(hv.w); a[7] += al * bfhi(hv.w);
        }
        const int c0 = cq * 8;
#pragma unroll
        for (int m2 = 0; m2 < 8; m2++) {
            a[m2] += bvec[c0 + m2];
            if (relu_flag) a[m2] = fmaxf(a[m2], 0.f);
        }
        uint4 o;
        o.x = (u32)f2bf(a[0]) | ((u32)f2bf(a[1]) << 16);
        o.y = (u32)f2bf(a[2]) | ((u32)f2bf(a[3]) << 16);
        o.z = (u32)f2bf(a[4]) | ((u32)f2bf(a[5]) << 16);
        o.w = (u32)f2bf(a[6]) | ((u32)f2bf(a[7]) << 16);
        hgo4[(g * Nn_ + n) * 16 + cq] = o;
    }
}

// ---------------- bf16 MFMA GEMM: C[M,ldc] = A[M,K]bf16 @ Bt[N,K]bf16^T + b1[n]+b2[n] (fp32)
__global__ __launch_bounds__(256) void k_gemm_mfma(const u16* __restrict__ A,
                                                   const u16* __restrict__ Bt,
                                                   float* __restrict__ Cm,
                                                   const float* __restrict__ b1,
                                                   const float* __restrict__ b2,
                                                   int K, int ldc) {
    __shared__ u16 ldsA[128 * 64];
    __shared__ u16 ldsB[128 * 64];
    const int w = threadIdx.x >> 6;
    const int lane = threadIdx.x & 63;
    const long bm = (long)blockIdx.x * 128;
    const int bn = blockIdx.y * 128;
    const int wm = (w & 1) * 64, wn = (w >> 1) * 64;
    const int q = lane >> 4, col = lane & 15;
    f32x4 acc[4][4] = {};
    for (int k0 = 0; k0 < K; k0 += 64) {
#pragma unroll
        for (int i = 0; i < 4; i++) {
            const int slot = (w * 4 + i) * 64 + lane;
            const int r = slot >> 3, cs = slot & 7;
            const int cg = cs ^ (r & 7);
            async16(A + (bm + r) * (long)K + k0 + cg * 8, ldsA + (w * 4 + i) * 512);
            async16(Bt + (long)(bn + r) * K + k0 + cg * 8, ldsB + (w * 4 + i) * 512);
        }
        __syncthreads();
#pragma unroll
        for (int kk = 0; kk < 2; kk++) {
            bf16x8 af[4], bfr[4];
#pragma unroll
            for (int mt = 0; mt < 4; mt++) {
                const int m = wm + mt * 16 + col;
                const int cs = (kk * 4 + q) ^ (m & 7);
                af[mt] = *(const bf16x8*)&ldsA[m * 64 + cs * 8];
            }
#pragma unroll
            for (int nt = 0; nt < 4; nt++) {
                const int n = wn + nt * 16 + col;
                const int cs = (kk * 4 + q) ^ (n & 7);
                bfr[nt] = *(const bf16x8*)&ldsB[n * 64 + cs * 8];
            }
#pragma unroll
            for (int mt = 0; mt < 4; mt++)
#pragma unroll
                for (int nt = 0; nt < 4; nt++)
                    acc[mt][nt] = __builtin_amdgcn_mfma_f32_16x16x32_bf16(af[mt], bfr[nt], acc[mt][nt], 0, 0, 0);
        }
        __syncthreads();
    }
#pragma unroll
    for (int mt = 0; mt < 4; mt++)
#pragma unroll
        for (int nt = 0; nt < 4; nt++) {
            const int cg = bn + wn + nt * 16 + col;
            const float bb = b1[cg] + b2[cg];
#pragma unroll
            for (int r = 0; r < 4; r++) {
                const long rg = bm + wm + mt * 16 + q * 4 + r;
                Cm[rg * ldc + cg] = acc[mt][nt][r] + bb;
            }
        }
}

// ---------------- LSTM recurrence: bf16-packed whh in regs + shortened critical path
// r13 PMC: whh-bf16 in 64 VGPRs got 102->90us (VALUBusy 49%). Remaining cost is the
// serial path: 128-FMA dependent chain + cell phase (5 transcendentals on 128/512
// threads between 2 barriers). This round: (a) 4 independent partial accumulators;
// (b) each thread applies its OWN gate's nonlinearity pre-barrier (gate = j>>7:
// i,f,o = sigmoid; g = tanh) so the serial cell phase is 2 FMA + 1 tanh;
// (c) c-state in a register (thread j<128 owns column j).
template <int OBF16>
__global__ __launch_bounds__(512, 1) void k_lstm(const float* __restrict__ XW,
                                                 const u16* __restrict__ whhb,
                                                 void* __restrict__ hseq) {
    const int b = blockIdx.x, j = threadIdx.x;
    u32 wp[64];   // 128 bf16 = 64 VGPRs
    const u32* wrow = (const u32*)(whhb + (long)j * OUT_);
#pragma unroll
    for (int k = 0; k < 64; k++) wp[k] = wrow[k];
    __shared__ __align__(16) float h_s[OUT_];
    __shared__ float gate_s[G4];
    float c_r = 0.f;
    if (j < OUT_) h_s[j] = 0.f;
    float xw = XW[((long)b * Tt + 0) * G4 + j];
    const int gate = j >> 7;   // 0:i 1:f 2:g 3:o
    __syncthreads();
    for (int t = 0; t < Tt; t++) {
        float xw_next = 0.f;
        if (t < Tt - 1) xw_next = XW[((long)b * Tt + t + 1) * G4 + j];
        float a0 = xw, a1 = 0.f, a2 = 0.f, a3 = 0.f;
#pragma unroll
        for (int k = 0; k < 32; k += 4) {
            const float4 h0 = ((const float4*)h_s)[k];
            const float4 h1 = ((const float4*)h_s)[k + 1];
            const float4 h2 = ((const float4*)h_s)[k + 2];
            const float4 h3 = ((const float4*)h_s)[k + 3];
            u32 p0 = wp[2 * k], p1 = wp[2 * k + 1];
            a0 += bflo(p0) * h0.x + bfhi(p0) * h0.y + bflo(p1) * h0.z + bfhi(p1) * h0.w;
            p0 = wp[2 * k + 2]; p1 = wp[2 * k + 3];
            a1 += bflo(p0) * h1.x + bfhi(p0) * h1.y + bflo(p1) * h1.z + bfhi(p1) * h1.w;
            p0 = wp[2 * k + 4]; p1 = wp[2 * k + 5];
            a2 += bflo(p0) * h2.x + bfhi(p0) * h2.y + bflo(p1) * h2.z + bfhi(p1) * h2.w;
            p0 = wp[2 * k + 6]; p1 = wp[2 * k + 7];
            a3 += bflo(p0) * h3.x + bfhi(p0) * h3.y + bflo(p1) * h3.z + bfhi(p1) * h3.w;
        }
        const float acc = (a0 + a1) + (a2 + a3);
        gate_s[j] = (gate == 2) ? tanhf(acc) : 1.f / (1.f + expf(-acc));
        __syncthreads();
        if (j < OUT_) {
            const float si = gate_s[j], sf = gate_s[OUT_ + j];
            const float gg = gate_s[2 * OUT_ + j], so = gate_s[3 * OUT_ + j];
            const float c = sf * c_r + si * gg;
            c_r = c;
            const float hh = so * tanhf(c);
            h_s[j] = hh;
            const long idx = ((long)b * Tt + t) * OUT_ + j;
            if (OBF16) ((u16*)hseq)[idx] = f2bf(hh);
            else       ((float*)hseq)[idx] = hh;
        }
        xw = xw_next;
        __syncthreads();
    }
}

// ---------------- attention pooling + FC
__global__ __launch_bounds__(64) void k_attn_fc(const float* __restrict__ h2,
                                                const float* __restrict__ attn_w,
                                                const float* __restrict__ attn_b,
                                                const float* __restrict__ fc_w,
                                                const float* __restrict__ fc_b,
                                                float* __restrict__ out) {
    const int b = blockIdx.x, t = threadIdx.x;
    __shared__ float aw[Tt];
    __shared__ float ctx[OUT_];
    const float* hb = h2 + (long)b * Tt * OUT_;
    float acc = 0.f;
    for (int d = 0; d < OUT_; d++) acc += hb[t * OUT_ + d] * attn_w[d];
    float sc = tanhf(acc + attn_b[0]);
    float m = sc;
#pragma unroll
    for (int o = 32; o > 0; o >>= 1) m = fmaxf(m, __shfl_xor(m, o));
    float ex = expf(sc - m);
    float sum = ex;
#pragma unroll
    for (int o = 32; o > 0; o >>= 1) sum += __shfl_xor(sum, o);
    aw[t] = ex / sum;
    __syncthreads();
    for (int d = t; d < OUT_; d += 64) {
        float c = 0.f;
        for (int tt = 0; tt < Tt; tt++) c += aw[tt] * hb[tt * OUT_ + d];
        ctx[d] = c;
    }
    __syncthreads();
    if (t < NCLS) {
        float o = fc_b[t];
        for (int d = 0; d < OUT_; d++) o += ctx[d] * fc_w[t * OUT_ + d];
        out[b * NCLS + t] = o;
    }
}

extern "C" void kernel_launch(void* const* d_in, const int* in_sizes, int n_in,
                              void* d_out, int out_size, void* d_ws, size_t ws_size,
                              hipStream_t stream) {
    const float* x          = (const float*)d_in[0];
    const int*   edge_index = (const int*)d_in[1];
    const float* gw[4]  = {(const float*)d_in[2], (const float*)d_in[6], (const float*)d_in[10], (const float*)d_in[14]};
    const float* gas[4] = {(const float*)d_in[3], (const float*)d_in[7], (const float*)d_in[11], (const float*)d_in[15]};
    const float* gad[4] = {(const float*)d_in[4], (const float*)d_in[8], (const float*)d_in[12], (const float*)d_in[16]};
    const float* gb[4]  = {(const float*)d_in[5], (const float*)d_in[9], (const float*)d_in[13], (const float*)d_in[17]};
    const float* wih0 = (const float*)d_in[18];
    const float* whh0 = (const float*)d_in[19];
    const float* bih0 = (const float*)d_in[20];
    const float* bhh0 = (const float*)d_in[21];
    const float* wih1 = (const float*)d_in[22];
    const float* whh1 = (const float*)d_in[23];
    const float* bih1 = (const float*)d_in[24];
    const float* bhh1 = (const float*)d_in[25];
    const float* attn_w = (const float*)d_in[26];
    const float* attn_b = (const float*)d_in[27];
    const float* fc_w   = (const float*)d_in[28];
    const float* fc_b   = (const float*)d_in[29];
    float* out = (float*)d_out;
    char* p = (char*)d_ws;

    // Workspace (~158.2 MB; 176.2 MB proven OK in round 2)
    u16*   hbuf  = (u16*)(p + 0L);              // 71,303,168 B
    float* aux   = (float*)(p + 71303168L);     //  4,456,448 B
    float* XW0   = (float*)(p + 75759616L);     // 33,554,432 B
    float* XW1   = (float*)(p + 109314048L);    // 33,554,432 B
    float* h2s   = (float*)(p + 142868480L);    //  8,388,608 B
    u16*   h1s   = (u16*)(p + 151257088L);      //  4,194,304 B
    u16*   wih0b = (u16*)(p + 155451392L);      //  2,228,224 B
    u16*   wih1b = (u16*)(p + 157679616L);      //    131,072 B
    u16*   whh0b = (u16*)(p + 157810688L);      //    131,072 B
    u16*   whh1b = (u16*)(p + 157941760L);      //    131,072 B
    u16*   wt1   = (u16*)(p + 158072832L);      //     32,768 B (x3)
    u16*   wt2   = (u16*)(p + 158105600L);
    u16*   wt3   = (u16*)(p + 158138368L);
    int*   csr   = (int*)(p + 158171136L);      //      1,044 B

    k_setup<<<1, 1, 0, stream>>>(edge_index, csr);
    k_convert_t128<<<64, 256, 0, stream>>>(gw[1], wt1);
    k_convert_t128<<<64, 256, 0, stream>>>(gw[2], wt2);
    k_convert_t128<<<64, 256, 0, stream>>>(gw[3], wt3);
    k_convert<<<(512 * 2176 + 255) / 256, 256, 0, stream>>>(wih0, wih0b, 512L * 2176);
    k_convert<<<256, 256, 0, stream>>>(wih1, wih1b, 512L * 128);
    k_convert<<<256, 256, 0, stream>>>(whh0, whh0b, 512L * 128);
    k_convert<<<256, 256, 0, stream>>>(whh1, whh1b, 512L * 128);

    // GAT layer 0 projection (+fp32 attn dots) then attention
    k_l0<<<Mg / 16, 256, 0, stream>>>(x, gw[0], gas[0], gad[0], hbuf, aux);
    k_gat_attn<<<Gg / GPB, 256, 0, stream>>>(hbuf, aux, gb[0], csr, 1);
    // layers 1..3: in-place MFMA GEMM with fp32 dot epilogue, then attention
    k_gemm_gat<<<Mg / 128, 256, 0, stream>>>(hbuf, wt1, gas[1], gad[1], aux);
    k_gat_attn<<<Gg / GPB, 256, 0, stream>>>(hbuf, aux, gb[1], csr, 0);
    k_gemm_gat<<<Mg / 128, 256, 0, stream>>>(hbuf, wt2, gas[2], gad[2], aux);
    k_gat_attn<<<Gg / GPB, 256, 0, stream>>>(hbuf, aux, gb[2], csr, 1);
    k_gemm_gat<<<Mg / 128, 256, 0, stream>>>(hbuf, wt3, gas[3], gad[3], aux);
    k_gat_attn<<<Gg / GPB, 256, 0, stream>>>(hbuf, aux, gb[3], csr, 0);

    // LSTM layer 0: input GEMM (hbuf == lstm_in [16384,2176] bf16) + recurrence
    k_gemm_mfma<<<dim3(Gg / 128, 4), 256, 0, stream>>>(hbuf, wih0b, XW0, bih0, bhh0, LSTM_IN, G4);
    k_lstm<1><<<Bb, 512, 0, stream>>>(XW0, whh0b, h1s);
    // LSTM layer 1
    k_gemm_mfma<<<dim3(Gg / 128, 4), 256, 0, stream>>>(h1s, wih1b, XW1, bih1, bhh1, OUT_, G4);
    k_lstm<0><<<Bb, 512, 0, stream>>>(XW1, whh1b, h2s);

    k_attn_fc<<<Bb, 64, 0, stream>>>(h2s, attn_w, attn_b, fc_w, fc_b, out);
}

// Round 15
// 711.198 us; speedup vs baseline: 2.0652x; 1.0309x over previous
//
#include <hip/hip_runtime.h>
#include <hip/hip_bf16.h>

// Problem constants
#define Bb 256
#define Nn_ 17
#define CIN 3
#define HID 64
#define CCH 128        // HEADS*HID
#define Gg 16384       // B*S
#define Ee 81          // 64 edges + 17 self loops
#define LSTM_IN 2176   // 17*128
#define OUT_ 128
#define G4 512         // 4*OUT
#define NCLS 10
#define Tt 64
#define Mg (Gg * Nn_)  // 278528

typedef unsigned short u16;
typedef unsigned int u32;
typedef __attribute__((ext_vector_type(8))) short bf16x8;
typedef __attribute__((ext_vector_type(4))) float f32x4;

__device__ __forceinline__ u16 f2bf(float f) {   // RNE fp32->bf16
    u32 u = __float_as_uint(f);
    u += 0x7fffu + ((u >> 16) & 1u);
    return (u16)(u >> 16);
}
__device__ __forceinline__ float bflo(u32 v) { return __uint_as_float(v << 16); }
__device__ __forceinline__ float bfhi(u32 v) { return __uint_as_float(v & 0xffff0000u); }

__device__ __forceinline__ void async16(const void* g, void* l) {
    __builtin_amdgcn_global_load_lds((__attribute__((address_space(1))) u32*)g,
                                     (__attribute__((address_space(3))) u32*)l, 16, 0, 0);
}

// ---------------- setup: build src/dst + dst-CSR (parallel edge staging, r15)
__global__ __launch_bounds__(128) void k_setup(const int* __restrict__ edge_index,
                                               int* __restrict__ csr) {
    __shared__ int eis[128];
    const int t = threadIdx.x;
    eis[t] = edge_index[t];        // parallel load (old single-thread version: ~128 serial
    __syncthreads();               // dependent global reads ~= 10us of pure latency)
    if (t == 0) {
        int* src = csr;                    // [81]
        int* dst = csr + Ee;               // [81]
        int* off = csr + 2 * Ee;           // [18]
        int* eid = csr + 2 * Ee + Nn_ + 1; // [81]
        int s_[Ee], d_[Ee];
        for (int e = 0; e < 64; e++) { s_[e] = eis[e]; d_[e] = eis[64 + e]; }
        for (int n = 0; n < Nn_; n++) { s_[64 + n] = n; d_[64 + n] = n; }
        int cnt[Nn_];
        for (int n = 0; n < Nn_; n++) cnt[n] = 0;
        for (int e = 0; e < Ee; e++) cnt[d_[e]]++;
        int offl[Nn_ + 1];
        offl[0] = 0;
        for (int n = 0; n < Nn_; n++) offl[n + 1] = offl[n] + cnt[n];
        int pos[Nn_];
        for (int n = 0; n < Nn_; n++) pos[n] = offl[n];
        for (int e = 0; e < Ee; e++) { src[e] = s_[e]; dst[e] = d_[e]; }
        for (int n = 0; n <= Nn_; n++) off[n] = offl[n];
        for (int e = 0; e < Ee; e++) eid[pos[d_[e]]++] = e;
    }
}

__global__ void k_convert(const float* __restrict__ in, u16* __restrict__ out, long n) {
    long i = (long)blockIdx.x * 256 + threadIdx.x;
    if (i < n) out[i] = f2bf(in[i]);
}

// ---------------- merged small-weight conversion (r15): 3 transposed GAT weights + 3 LSTM mats
// items 0..49151: wt transposes (3 x 16384); items 49152..245759: straight converts (3 x 65536)
__global__ __launch_bounds__(256) void k_convert_small(
    const float* __restrict__ gw1, const float* __restrict__ gw2, const float* __restrict__ gw3,
    const float* __restrict__ wih1, const float* __restrict__ whh0, const float* __restrict__ whh1,
    u16* __restrict__ wt1, u16* __restrict__ wt2, u16* __restrict__ wt3,
    u16* __restrict__ wih1b, u16* __restrict__ whh0b, u16* __restrict__ whh1b) {
    const int i = blockIdx.x * 256 + threadIdx.x;
    if (i < 49152) {
        const int which = i / 16384, r = i % 16384;
        const float* s = (which == 0) ? gw1 : (which == 1) ? gw2 : gw3;
        u16* d = (which == 0) ? wt1 : (which == 1) ? wt2 : wt3;
        const int n = r >> 7, k = r & 127;
        d[r] = f2bf(s[k * 128 + n]);
    } else {
        const int ii = i - 49152;
        const int which = ii / 65536, r = ii % 65536;
        const float* s = (which == 0) ? wih1 : (which == 1) ? whh0 : whh1;
        u16* d = (which == 0) ? wih1b : (which == 1) ? whh0b : whh1b;
        d[r] = f2bf(s[r]);
    }
}

// ---------------- GAT layer 0: h[Mg,128]=x@W0 (bf16) + aux[Mg,4]=x@(W0@a) (fp32)
__global__ __launch_bounds__(256) void k_l0(const float* __restrict__ x,
                                            const float* __restrict__ W0,
                                            const float* __restrict__ gas0,
                                            const float* __restrict__ gad0,
                                            u16* __restrict__ h, float* __restrict__ aux) {
    __shared__ float ws[3 * 128];
    __shared__ float w0a[12];   // [ci][j]  j: src_h0,src_h1,dst_h0,dst_h1
    const int t = threadIdx.x;
    for (int i = t; i < 384; i += 256) ws[i] = W0[i];
    __syncthreads();
    if (t < 12) {
        int ci = t >> 2, j = t & 3;
        const float* a = (j < 2) ? gas0 : gad0;
        int hh = j & 1;
        float s = 0.f;
        for (int d = 0; d < HID; d++) s += ws[ci * 128 + hh * 64 + d] * a[hh * 64 + d];
        w0a[t] = s;
    }
    __syncthreads();
    const long row = (long)blockIdx.x * 16 + (t >> 4);
    const int c0 = (t & 15) * 8;
    const float x0 = x[row * 3 + 0], x1 = x[row * 3 + 1], x2 = x[row * 3 + 2];
    union { uint4 u; u16 s[8]; } o;
#pragma unroll
    for (int j = 0; j < 8; j++)
        o.s[j] = f2bf(x0 * ws[c0 + j] + x1 * ws[128 + c0 + j] + x2 * ws[256 + c0 + j]);
    *(uint4*)(h + row * 128 + c0) = o.u;
    if ((t & 15) < 4) {
        int j = t & 3;
        aux[row * 4 + j] = x0 * w0a[j] + x1 * w0a[4 + j] + x2 * w0a[8 + j];
    }
}

// ---------------- GAT MFMA GEMM (in-place): hbuf = hbuf @ W ; aux = fp32 dots vs a_src/a_dst
__global__ __launch_bounds__(256) void k_gemm_gat(u16* __restrict__ HB,
                                                  const u16* __restrict__ Wt,
                                                  const float* __restrict__ a_src,
                                                  const float* __restrict__ a_dst,
                                                  float* __restrict__ aux) {
    __shared__ u16 ldsA[128 * 128];  // 32 KB
    __shared__ float avec[128], dvec[128];
    const int t = threadIdx.x;
    const int w = t >> 6, lane = t & 63;
    const int q = lane >> 4, col = lane & 15;
    const long bm = (long)blockIdx.x * 128;
    const int wm = w * 32;

    if (t < 128) avec[t] = a_src[t];
    else dvec[t - 128] = a_dst[t - 128];

#pragma unroll
    for (int i = 0; i < 8; i++) {
        const int slot = (w * 8 + i) * 64 + lane;
        const int r = slot >> 4, cs = slot & 15;
        const int cg = cs ^ (r & 15);
        async16(HB + (bm + r) * 128 + cg * 8, ldsA + (w * 8 + i) * 512);
    }
    __syncthreads();

    f32x4 acc[2][8] = {};
#pragma unroll
    for (int ks = 0; ks < 4; ks++) {
        const int ck = ks * 4 + q;
        bf16x8 af[2];
#pragma unroll
        for (int mt = 0; mt < 2; mt++) {
            const int m = wm + mt * 16 + col;
            af[mt] = *(const bf16x8*)&ldsA[m * 128 + ((ck ^ (m & 15)) << 3)];
        }
#pragma unroll
        for (int nt = 0; nt < 8; nt++) {
            bf16x8 bf = *(const bf16x8*)&Wt[(nt * 16 + col) * 128 + ck * 8];
            acc[0][nt] = __builtin_amdgcn_mfma_f32_16x16x32_bf16(af[0], bf, acc[0][nt], 0, 0, 0);
            acc[1][nt] = __builtin_amdgcn_mfma_f32_16x16x32_bf16(af[1], bf, acc[1][nt], 0, 0, 0);
        }
    }
    __syncthreads();
#pragma unroll
    for (int mt = 0; mt < 2; mt++) {
#pragma unroll
        for (int nt = 0; nt < 8; nt++) {
            const int cg = nt * 16 + col;
#pragma unroll
            for (int r = 0; r < 4; r++) {
                const long rg = bm + wm + mt * 16 + q * 4 + r;
                HB[rg * 128 + cg] = f2bf(acc[mt][nt][r]);
            }
        }
#pragma unroll
        for (int r = 0; r < 4; r++) {
            float s0 = 0.f, s1 = 0.f, d0 = 0.f, d1 = 0.f;
#pragma unroll
            for (int nt = 0; nt < 4; nt++) {
                const float v = acc[mt][nt][r];
                s0 += v * avec[nt * 16 + col];
                d0 += v * dvec[nt * 16 + col];
            }
#pragma unroll
            for (int nt = 4; nt < 8; nt++) {
                const float v = acc[mt][nt][r];
                s1 += v * avec[nt * 16 + col];
                d1 += v * dvec[nt * 16 + col];
            }
#pragma unroll
            for (int o = 1; o < 16; o <<= 1) {
                s0 += __shfl_xor(s0, o);
                s1 += __shfl_xor(s1, o);
                d0 += __shfl_xor(d0, o);
                d1 += __shfl_xor(d1, o);
            }
            if (col == 0) {
                const long rg = bm + wm + mt * 16 + q * 4 + r;
                aux[rg * 4 + 0] = s0;
                aux[rg * 4 + 1] = s1;
                aux[rg * 4 + 2] = d0;
                aux[rg * 4 + 3] = d1;
            }
        }
    }
}

// ---------------- GAT attention (4 graphs/block), 16B-vectorized staging + aggregation
#define GPB 4
__global__ __launch_bounds__(256) void k_gat_attn(u16* __restrict__ h,
                                                  const float* __restrict__ aux,
                                                  const float* __restrict__ bias,
                                                  const int* __restrict__ csr,
                                                  int relu_flag) {
    __shared__ __align__(16) u32 hs[GPB * Nn_ * 64];   // [g][n][cp]
    __shared__ float asd[GPB * Nn_ * 4];
    __shared__ float ev[GPB][162];
    __shared__ float mS[GPB][34], dS[GPB][34];
    __shared__ float bvec[128];
    __shared__ int srcS[Ee], dstS[Ee], offS[Nn_ + 1], eidS[Ee];
    const int t = threadIdx.x;
    const long g0 = (long)blockIdx.x * GPB;

    if (t < Ee) { srcS[t] = csr[t]; dstS[t] = csr[Ee + t]; eidS[t] = csr[180 + t]; }
    if (t >= 128 && t < 128 + Nn_ + 1) offS[t - 128] = csr[162 + t - 128];
    if (t < 128) bvec[t] = bias[t];
    {
        const uint4* hg4 = (const uint4*)((const u32*)h + g0 * 1088);
        for (int i = t; i < GPB * Nn_ * 16; i += 256) ((uint4*)hs)[i] = hg4[i];
        const float* ag = aux + g0 * 68;
        for (int i = t; i < GPB * Nn_ * 4; i += 256) asd[i] = ag[i];   // 272 > 256 (r8 bugfix)
    }
    __syncthreads();
    for (int i = t; i < GPB * 162; i += 256) {
        const int g = i / 162, rem = i % 162, e = rem >> 1, hh = rem & 1;
        float v = asd[(g * Nn_ + srcS[e]) * 4 + hh] + asd[(g * Nn_ + dstS[e]) * 4 + 2 + hh];
        ev[g][rem] = (v > 0.f) ? v : 0.2f * v;
    }
    __syncthreads();
    if (t < GPB * 34) {
        const int g = t / 34, rem = t % 34, n = rem >> 1, hh = rem & 1;
        const int p0 = offS[n], p1 = offS[n + 1];
        float m = -1e30f;
        for (int p = p0; p < p1; p++) m = fmaxf(m, ev[g][eidS[p] * 2 + hh]);
        float den = 0.f;
        for (int p = p0; p < p1; p++) den += expf(ev[g][eidS[p] * 2 + hh] - m);
        mS[g][rem] = m;
        dS[g][rem] = den;
    }
    __syncthreads();
    for (int i = t; i < GPB * 162; i += 256) {
        const int g = i / 162, rem = i % 162, e = rem >> 1, hh = rem & 1;
        const int n = dstS[e];
        ev[g][rem] = expf(ev[g][rem] - mS[g][n * 2 + hh]) / (dS[g][n * 2 + hh] + 1e-16f);
    }
    __syncthreads();
    // aggregation: items = (g, n, cq), each covers 8 bf16 columns (one uint4)
    uint4* hgo4 = (uint4*)((u32*)h + g0 * 1088);
    for (int i = t; i < GPB * Nn_ * 16; i += 256) {
        const int g = i / (Nn_ * 16), rem = i % (Nn_ * 16);
        const int n = rem >> 4, cq = rem & 15, hh = cq >> 3;
        const int p0 = offS[n], p1 = offS[n + 1];
        float a[8] = {};
        for (int p = p0; p < p1; p++) {
            const int e = eidS[p];
            const uint4 hv = ((const uint4*)hs)[(g * Nn_ + srcS[e]) * 16 + cq];
            const float al = ev[g][e * 2 + hh];
            a[0] += al * bflo(hv.x); a[1] += al * bfhi(hv.x);
            a[2] += al * bflo(hv.y); a[3] += al * bfhi(hv.y);
            a[4] += al * bflo(hv.z); a[5] += al * bfhi(hv.z);
            a[6] += al * bflo(hv.w); a[7] += al * bfhi(hv.w);
        }
        const int c0 = cq * 8;
#pragma unroll
        for (int m2 = 0; m2 < 8; m2++) {
            a[m2] += bvec[c0 + m2];
            if (relu_flag) a[m2] = fmaxf(a[m2], 0.f);
        }
        uint4 o;
        o.x = (u32)f2bf(a[0]) | ((u32)f2bf(a[1]) << 16);
        o.y = (u32)f2bf(a[2]) | ((u32)f2bf(a[3]) << 16);
        o.z = (u32)f2bf(a[4]) | ((u32)f2bf(a[5]) << 16);
        o.w = (u32)f2bf(a[6]) | ((u32)f2bf(a[7]) << 16);
        hgo4[(g * Nn_ + n) * 16 + cq] = o;
    }
}

// ---------------- bf16 MFMA GEMM: C[M,ldc] = A[M,K]bf16 @ Bt[N,K]bf16^T + b1[n]+b2[n] (fp32)
__global__ __launch_bounds__(256) void k_gemm_mfma(const u16* __restrict__ A,
                                                   const u16* __restrict__ Bt,
                                                   float* __restrict__ Cm,
                                                   const float* __restrict__ b1,
                                                   const float* __restrict__ b2,
                                                   int K, int ldc) {
    __shared__ u16 ldsA[128 * 64];
    __shared__ u16 ldsB[128 * 64];
    const int w = threadIdx.x >> 6;
    const int lane = threadIdx.x & 63;
    const long bm = (long)blockIdx.x * 128;
    const int bn = blockIdx.y * 128;
    const int wm = (w & 1) * 64, wn = (w >> 1) * 64;
    const int q = lane >> 4, col = lane & 15;
    f32x4 acc[4][4] = {};
    for (int k0 = 0; k0 < K; k0 += 64) {
#pragma unroll
        for (int i = 0; i < 4; i++) {
            const int slot = (w * 4 + i) * 64 + lane;
            const int r = slot >> 3, cs = slot & 7;
            const int cg = cs ^ (r & 7);
            async16(A + (bm + r) * (long)K + k0 + cg * 8, ldsA + (w * 4 + i) * 512);
            async16(Bt + (long)(bn + r) * K + k0 + cg * 8, ldsB + (w * 4 + i) * 512);
        }
        __syncthreads();
#pragma unroll
        for (int kk = 0; kk < 2; kk++) {
            bf16x8 af[4], bfr[4];
#pragma unroll
            for (int mt = 0; mt < 4; mt++) {
                const int m = wm + mt * 16 + col;
                const int cs = (kk * 4 + q) ^ (m & 7);
                af[mt] = *(const bf16x8*)&ldsA[m * 64 + cs * 8];
            }
#pragma unroll
            for (int nt = 0; nt < 4; nt++) {
                const int n = wn + nt * 16 + col;
                const int cs = (kk * 4 + q) ^ (n & 7);
                bfr[nt] = *(const bf16x8*)&ldsB[n * 64 + cs * 8];
            }
#pragma unroll
            for (int mt = 0; mt < 4; mt++)
#pragma unroll
                for (int nt = 0; nt < 4; nt++)
                    acc[mt][nt] = __builtin_amdgcn_mfma_f32_16x16x32_bf16(af[mt], bfr[nt], acc[mt][nt], 0, 0, 0);
        }
        __syncthreads();
    }
#pragma unroll
    for (int mt = 0; mt < 4; mt++)
#pragma unroll
        for (int nt = 0; nt < 4; nt++) {
            const int cg = bn + wn + nt * 16 + col;
            const float bb = b1[cg] + b2[cg];
#pragma unroll
            for (int r = 0; r < 4; r++) {
                const long rg = bm + wm + mt * 16 + q * 4 + r;
                Cm[rg * ldc + cg] = acc[mt][nt][r] + bb;
            }
        }
}

// ---------------- LSTM recurrence: whh unpacked ONCE to fp32 regs (r15)
// r14 PMC: 76.5us, VALUBusy 55%. MAC loop was 128 FMA + ~96 per-step bf16 unpack VALU
// ops (shift/mask) repeated 64 steps on register-resident packed weights. Hoist the
// unpack: wf[128] fp32 registers built once before the time loop -> pure-FMA MAC body.
// VGPR ~200 -> still 2 waves/SIMD (cliff at 256). Gate-split nonlinearity + reg c-state
// + XW[t+1] prefetch kept from r14.
template <int OBF16>
__global__ __launch_bounds__(512, 1) void k_lstm(const float* __restrict__ XW,
                                                 const u16* __restrict__ whhb,
                                                 void* __restrict__ hseq) {
    const int b = blockIdx.x, j = threadIdx.x;
    float wf[128];
    {
        const u32* wrow = (const u32*)(whhb + (long)j * OUT_);
#pragma unroll
        for (int k = 0; k < 64; k++) {
            const u32 pv = wrow[k];
            wf[2 * k]     = bflo(pv);
            wf[2 * k + 1] = bfhi(pv);
        }
    }
    __shared__ __align__(16) float h_s[OUT_];
    __shared__ float gate_s[G4];
    float c_r = 0.f;
    if (j < OUT_) h_s[j] = 0.f;
    float xw = XW[((long)b * Tt + 0) * G4 + j];
    const int gate = j >> 7;   // 0:i 1:f 2:g 3:o
    __syncthreads();
    for (int t = 0; t < Tt; t++) {
        float xw_next = 0.f;
        if (t < Tt - 1) xw_next = XW[((long)b * Tt + t + 1) * G4 + j];
        float a0 = xw, a1 = 0.f, a2 = 0.f, a3 = 0.f;
#pragma unroll
        for (int k = 0; k < 8; k++) {
            const float4 h0 = ((const float4*)h_s)[k];
            const float4 h1 = ((const float4*)h_s)[8 + k];
            const float4 h2 = ((const float4*)h_s)[16 + k];
            const float4 h3 = ((const float4*)h_s)[24 + k];
            a0 += wf[4 * k + 0] * h0.x + wf[4 * k + 1] * h0.y
                + wf[4 * k + 2] * h0.z + wf[4 * k + 3] * h0.w;
            a1 += wf[32 + 4 * k + 0] * h1.x + wf[32 + 4 * k + 1] * h1.y
                + wf[32 + 4 * k + 2] * h1.z + wf[32 + 4 * k + 3] * h1.w;
            a2 += wf[64 + 4 * k + 0] * h2.x + wf[64 + 4 * k + 1] * h2.y
                + wf[64 + 4 * k + 2] * h2.z + wf[64 + 4 * k + 3] * h2.w;
            a3 += wf[96 + 4 * k + 0] * h3.x + wf[96 + 4 * k + 1] * h3.y
                + wf[96 + 4 * k + 2] * h3.z + wf[96 + 4 * k + 3] * h3.w;
        }
        const float acc = (a0 + a1) + (a2 + a3);
        gate_s[j] = (gate == 2) ? tanhf(acc) : 1.f / (1.f + expf(-acc));
        __syncthreads();
        if (j < OUT_) {
            const float si = gate_s[j], sf = gate_s[OUT_ + j];
            const float gg = gate_s[2 * OUT_ + j], so = gate_s[3 * OUT_ + j];
            const float c = sf * c_r + si * gg;
            c_r = c;
            const float hh = so * tanhf(c);
            h_s[j] = hh;
            const long idx = ((long)b * Tt + t) * OUT_ + j;
            if (OBF16) ((u16*)hseq)[idx] = f2bf(hh);
            else       ((float*)hseq)[idx] = hh;
        }
        xw = xw_next;
        __syncthreads();
    }
}

// ---------------- attention pooling + FC
__global__ __launch_bounds__(64) void k_attn_fc(const float* __restrict__ h2,
                                                const float* __restrict__ attn_w,
                                                const float* __restrict__ attn_b,
                                                const float* __restrict__ fc_w,
                                                const float* __restrict__ fc_b,
                                                float* __restrict__ out) {
    const int b = blockIdx.x, t = threadIdx.x;
    __shared__ float aw[Tt];
    __shared__ float ctx[OUT_];
    const float* hb = h2 + (long)b * Tt * OUT_;
    float acc = 0.f;
    for (int d = 0; d < OUT_; d++) acc += hb[t * OUT_ + d] * attn_w[d];
    float sc = tanhf(acc + attn_b[0]);
    float m = sc;
#pragma unroll
    for (int o = 32; o > 0; o >>= 1) m = fmaxf(m, __shfl_xor(m, o));
    float ex = expf(sc - m);
    float sum = ex;
#pragma unroll
    for (int o = 32; o > 0; o >>= 1) sum += __shfl_xor(sum, o);
    aw[t] = ex / sum;
    __syncthreads();
    for (int d = t; d < OUT_; d += 64) {
        float c = 0.f;
        for (int tt = 0; tt < Tt; tt++) c += aw[tt] * hb[tt * OUT_ + d];
        ctx[d] = c;
    }
    __syncthreads();
    if (t < NCLS) {
        float o = fc_b[t];
        for (int d = 0; d < OUT_; d++) o += ctx[d] * fc_w[t * OUT_ + d];
        out[b * NCLS + t] = o;
    }
}

extern "C" void kernel_launch(void* const* d_in, const int* in_sizes, int n_in,
                              void* d_out, int out_size, void* d_ws, size_t ws_size,
                              hipStream_t stream) {
    const float* x          = (const float*)d_in[0];
    const int*   edge_index = (const int*)d_in[1];
    const float* gw[4]  = {(const float*)d_in[2], (const float*)d_in[6], (const float*)d_in[10], (const float*)d_in[14]};
    const float* gas[4] = {(const float*)d_in[3], (const float*)d_in[7], (const float*)d_in[11], (const float*)d_in[15]};
    const float* gad[4] = {(const float*)d_in[4], (const float*)d_in[8], (const float*)d_in[12], (const float*)d_in[16]};
    const float* gb[4]  = {(const float*)d_in[5], (const float*)d_in[9], (const float*)d_in[13], (const float*)d_in[17]};
    const float* wih0 = (const float*)d_in[18];
    const float* whh0 = (const float*)d_in[19];
    const float* bih0 = (const float*)d_in[20];
    const float* bhh0 = (const float*)d_in[21];
    const float* wih1 = (const float*)d_in[22];
    const float* whh1 = (const float*)d_in[23];
    const float* bih1 = (const float*)d_in[24];
    const float* bhh1 = (const float*)d_in[25];
    const float* attn_w = (const float*)d_in[26];
    const float* attn_b = (const float*)d_in[27];
    const float* fc_w   = (const float*)d_in[28];
    const float* fc_b   = (const float*)d_in[29];
    float* out = (float*)d_out;
    char* p = (char*)d_ws;

    // Workspace (~158.2 MB; 176.2 MB proven OK in round 2)
    u16*   hbuf  = (u16*)(p + 0L);              // 71,303,168 B
    float* aux   = (float*)(p + 71303168L);     //  4,456,448 B
    float* XW0   = (float*)(p + 75759616L);     // 33,554,432 B
    float* XW1   = (float*)(p + 109314048L);    // 33,554,432 B
    float* h2s   = (float*)(p + 142868480L);    //  8,388,608 B
    u16*   h1s   = (u16*)(p + 151257088L);      //  4,194,304 B
    u16*   wih0b = (u16*)(p + 155451392L);      //  2,228,224 B
    u16*   wih1b = (u16*)(p + 157679616L);      //    131,072 B
    u16*   whh0b = (u16*)(p + 157810688L);      //    131,072 B
    u16*   whh1b = (u16*)(p + 157941760L);      //    131,072 B
    u16*   wt1   = (u16*)(p + 158072832L);      //     32,768 B (x3)
    u16*   wt2   = (u16*)(p + 158105600L);
    u16*   wt3   = (u16*)(p + 158138368L);
    int*   csr   = (int*)(p + 158171136L);      //      1,044 B

    k_setup<<<1, 128, 0, stream>>>(edge_index, csr);
    k_convert_small<<<960, 256, 0, stream>>>(gw[1], gw[2], gw[3], wih1, whh0, whh1,
                                             wt1, wt2, wt3, wih1b, whh0b, whh1b);
    k_convert<<<(512 * 2176 + 255) / 256, 256, 0, stream>>>(wih0, wih0b, 512L * 2176);

    // GAT layer 0 projection (+fp32 attn dots) then attention
    k_l0<<<Mg / 16, 256, 0, stream>>>(x, gw[0], gas[0], gad[0], hbuf, aux);
    k_gat_attn<<<Gg / GPB, 256, 0, stream>>>(hbuf, aux, gb[0], csr, 1);
    // layers 1..3: in-place MFMA GEMM with fp32 dot epilogue, then attention
    k_gemm_gat<<<Mg / 128, 256, 0, stream>>>(hbuf, wt1, gas[1], gad[1], aux);
    k_gat_attn<<<Gg / GPB, 256, 0, stream>>>(hbuf, aux, gb[1], csr, 0);
    k_gemm_gat<<<Mg / 128, 256, 0, stream>>>(hbuf, wt2, gas[2], gad[2], aux);
    k_gat_attn<<<Gg / GPB, 256, 0, stream>>>(hbuf, aux, gb[2], csr, 1);
    k_gemm_gat<<<Mg / 128, 256, 0, stream>>>(hbuf, wt3, gas[3], gad[3], aux);
    k_gat_attn<<<Gg / GPB, 256, 0, stream>>>(hbuf, aux, gb[3], csr, 0);

    // LSTM layer 0: input GEMM (hbuf == lstm_in [16384,2176] bf16) + recurrence
    k_gemm_mfma<<<dim3(Gg / 128, 4), 256, 0, stream>>>(hbuf, wih0b, XW0, bih0, bhh0, LSTM_IN, G4);
    k_lstm<1><<<Bb, 512, 0, stream>>>(XW0, whh0b, h1s);
    // LSTM layer 1
    k_gemm_mfma<<<dim3(Gg / 128, 4), 256, 0, stream>>>(h1s, wih1b, XW1, bih1, bhh1, OUT_, G4);
    k_lstm<0><<<Bb, 512, 0, stream>>>(XW1, whh1b, h2s);

    k_attn_fc<<<Bb, 64, 0, stream>>>(h2s, attn_w, attn_b, fc_w, fc_b, out);
}

// Round 16
// 685.344 us; speedup vs baseline: 2.1431x; 1.0377x over previous
//
#include <hip/hip_runtime.h>
#include <hip/hip_bf16.h>
#include <hip/hip_fp16.h>

// Problem constants
#define Bb 256
#define Nn_ 17
#define CIN 3
#define HID 64
#define CCH 128        // HEADS*HID
#define Gg 16384       // B*S
#define Ee 81          // 64 edges + 17 self loops
#define LSTM_IN 2176   // 17*128
#define OUT_ 128
#define G4 512         // 4*OUT
#define NCLS 10
#define Tt 64
#define Mg (Gg * Nn_)  // 278528

typedef unsigned short u16;
typedef unsigned int u32;
typedef __attribute__((ext_vector_type(8))) short bf16x8;
typedef __attribute__((ext_vector_type(4))) float f32x4;
typedef _Float16 h2f __attribute__((ext_vector_type(2)));

__device__ __forceinline__ u16 f2bf(float f) {   // RNE fp32->bf16
    u32 u = __float_as_uint(f);
    u += 0x7fffu + ((u >> 16) & 1u);
    return (u16)(u >> 16);
}
__device__ __forceinline__ float bflo(u32 v) { return __uint_as_float(v << 16); }
__device__ __forceinline__ float bfhi(u32 v) { return __uint_as_float(v & 0xffff0000u); }
__device__ __forceinline__ u16 f2h(float f) {    // RNE fp32->fp16
    _Float16 h = (_Float16)f;
    return *(u16*)&h;
}

// packed half2 dot-accumulate: acc += w.lo*h.lo + w.hi*h.hi
__device__ __forceinline__ float dot2acc(u32 w, u32 h, float acc) {
#if __has_builtin(__builtin_amdgcn_fdot2)
    return __builtin_amdgcn_fdot2(*(h2f*)&w, *(h2f*)&h, acc, false);
#else
    const __half2 wv = *(__half2*)&w, hv = *(__half2*)&h;
    return acc + __half2float(wv.x) * __half2float(hv.x)
               + __half2float(wv.y) * __half2float(hv.y);
#endif
}

__device__ __forceinline__ void async16(const void* g, void* l) {
    __builtin_amdgcn_global_load_lds((__attribute__((address_space(1))) u32*)g,
                                     (__attribute__((address_space(3))) u32*)l, 16, 0, 0);
}

// ---------------- setup: build src/dst + dst-CSR (parallel edge staging)
__global__ __launch_bounds__(128) void k_setup(const int* __restrict__ edge_index,
                                               int* __restrict__ csr) {
    __shared__ int eis[128];
    const int t = threadIdx.x;
    eis[t] = edge_index[t];
    __syncthreads();
    if (t == 0) {
        int* src = csr;                    // [81]
        int* dst = csr + Ee;               // [81]
        int* off = csr + 2 * Ee;           // [18]
        int* eid = csr + 2 * Ee + Nn_ + 1; // [81]
        int s_[Ee], d_[Ee];
        for (int e = 0; e < 64; e++) { s_[e] = eis[e]; d_[e] = eis[64 + e]; }
        for (int n = 0; n < Nn_; n++) { s_[64 + n] = n; d_[64 + n] = n; }
        int cnt[Nn_];
        for (int n = 0; n < Nn_; n++) cnt[n] = 0;
        for (int e = 0; e < Ee; e++) cnt[d_[e]]++;
        int offl[Nn_ + 1];
        offl[0] = 0;
        for (int n = 0; n < Nn_; n++) offl[n + 1] = offl[n] + cnt[n];
        int pos[Nn_];
        for (int n = 0; n < Nn_; n++) pos[n] = offl[n];
        for (int e = 0; e < Ee; e++) { src[e] = s_[e]; dst[e] = d_[e]; }
        for (int n = 0; n <= Nn_; n++) off[n] = offl[n];
        for (int e = 0; e < Ee; e++) eid[pos[d_[e]]++] = e;
    }
}

__global__ void k_convert(const float* __restrict__ in, u16* __restrict__ out, long n) {
    long i = (long)blockIdx.x * 256 + threadIdx.x;
    if (i < n) out[i] = f2bf(in[i]);
}

// ---------------- merged small-weight conversion: 3 transposed GAT weights (bf16),
// wih1 (bf16 for MFMA), whh0/whh1 (f16 for the dot2 recurrence)
__global__ __launch_bounds__(256) void k_convert_small(
    const float* __restrict__ gw1, const float* __restrict__ gw2, const float* __restrict__ gw3,
    const float* __restrict__ wih1, const float* __restrict__ whh0, const float* __restrict__ whh1,
    u16* __restrict__ wt1, u16* __restrict__ wt2, u16* __restrict__ wt3,
    u16* __restrict__ wih1b, u16* __restrict__ whh0h, u16* __restrict__ whh1h) {
    const int i = blockIdx.x * 256 + threadIdx.x;
    if (i < 49152) {
        const int which = i / 16384, r = i % 16384;
        const float* s = (which == 0) ? gw1 : (which == 1) ? gw2 : gw3;
        u16* d = (which == 0) ? wt1 : (which == 1) ? wt2 : wt3;
        const int n = r >> 7, k = r & 127;
        d[r] = f2bf(s[k * 128 + n]);
    } else {
        const int ii = i - 49152;
        const int which = ii / 65536, r = ii % 65536;
        if (which == 0) wih1b[r] = f2bf(wih1[r]);
        else if (which == 1) whh0h[r] = f2h(whh0[r]);
        else whh1h[r] = f2h(whh1[r]);
    }
}

// ---------------- GAT layer 0: h[Mg,128]=x@W0 (bf16) + aux[Mg,4]=x@(W0@a) (fp32)
__global__ __launch_bounds__(256) void k_l0(const float* __restrict__ x,
                                            const float* __restrict__ W0,
                                            const float* __restrict__ gas0,
                                            const float* __restrict__ gad0,
                                            u16* __restrict__ h, float* __restrict__ aux) {
    __shared__ float ws[3 * 128];
    __shared__ float w0a[12];   // [ci][j]  j: src_h0,src_h1,dst_h0,dst_h1
    const int t = threadIdx.x;
    for (int i = t; i < 384; i += 256) ws[i] = W0[i];
    __syncthreads();
    if (t < 12) {
        int ci = t >> 2, j = t & 3;
        const float* a = (j < 2) ? gas0 : gad0;
        int hh = j & 1;
        float s = 0.f;
        for (int d = 0; d < HID; d++) s += ws[ci * 128 + hh * 64 + d] * a[hh * 64 + d];
        w0a[t] = s;
    }
    __syncthreads();
    const long row = (long)blockIdx.x * 16 + (t >> 4);
    const int c0 = (t & 15) * 8;
    const float x0 = x[row * 3 + 0], x1 = x[row * 3 + 1], x2 = x[row * 3 + 2];
    union { uint4 u; u16 s[8]; } o;
#pragma unroll
    for (int j = 0; j < 8; j++)
        o.s[j] = f2bf(x0 * ws[c0 + j] + x1 * ws[128 + c0 + j] + x2 * ws[256 + c0 + j]);
    *(uint4*)(h + row * 128 + c0) = o.u;
    if ((t & 15) < 4) {
        int j = t & 3;
        aux[row * 4 + j] = x0 * w0a[j] + x1 * w0a[4 + j] + x2 * w0a[8 + j];
    }
}

// ---------------- GAT MFMA GEMM (in-place): hbuf = hbuf @ W ; aux = fp32 dots vs a_src/a_dst
__global__ __launch_bounds__(256) void k_gemm_gat(u16* __restrict__ HB,
                                                  const u16* __restrict__ Wt,
                                                  const float* __restrict__ a_src,
                                                  const float* __restrict__ a_dst,
                                                  float* __restrict__ aux) {
    __shared__ u16 ldsA[128 * 128];  // 32 KB
    __shared__ float avec[128], dvec[128];
    const int t = threadIdx.x;
    const int w = t >> 6, lane = t & 63;
    const int q = lane >> 4, col = lane & 15;
    const long bm = (long)blockIdx.x * 128;
    const int wm = w * 32;

    if (t < 128) avec[t] = a_src[t];
    else dvec[t - 128] = a_dst[t - 128];

#pragma unroll
    for (int i = 0; i < 8; i++) {
        const int slot = (w * 8 + i) * 64 + lane;
        const int r = slot >> 4, cs = slot & 15;
        const int cg = cs ^ (r & 15);
        async16(HB + (bm + r) * 128 + cg * 8, ldsA + (w * 8 + i) * 512);
    }
    __syncthreads();

    f32x4 acc[2][8] = {};
#pragma unroll
    for (int ks = 0; ks < 4; ks++) {
        const int ck = ks * 4 + q;
        bf16x8 af[2];
#pragma unroll
        for (int mt = 0; mt < 2; mt++) {
            const int m = wm + mt * 16 + col;
            af[mt] = *(const bf16x8*)&ldsA[m * 128 + ((ck ^ (m & 15)) << 3)];
        }
#pragma unroll
        for (int nt = 0; nt < 8; nt++) {
            bf16x8 bf = *(const bf16x8*)&Wt[(nt * 16 + col) * 128 + ck * 8];
            acc[0][nt] = __builtin_amdgcn_mfma_f32_16x16x32_bf16(af[0], bf, acc[0][nt], 0, 0, 0);
            acc[1][nt] = __builtin_amdgcn_mfma_f32_16x16x32_bf16(af[1], bf, acc[1][nt], 0, 0, 0);
        }
    }
    __syncthreads();
#pragma unroll
    for (int mt = 0; mt < 2; mt++) {
#pragma unroll
        for (int nt = 0; nt < 8; nt++) {
            const int cg = nt * 16 + col;
#pragma unroll
            for (int r = 0; r < 4; r++) {
                const long rg = bm + wm + mt * 16 + q * 4 + r;
                HB[rg * 128 + cg] = f2bf(acc[mt][nt][r]);
            }
        }
#pragma unroll
        for (int r = 0; r < 4; r++) {
            float s0 = 0.f, s1 = 0.f, d0 = 0.f, d1 = 0.f;
#pragma unroll
            for (int nt = 0; nt < 4; nt++) {
                const float v = acc[mt][nt][r];
                s0 += v * avec[nt * 16 + col];
                d0 += v * dvec[nt * 16 + col];
            }
#pragma unroll
            for (int nt = 4; nt < 8; nt++) {
                const float v = acc[mt][nt][r];
                s1 += v * avec[nt * 16 + col];
                d1 += v * dvec[nt * 16 + col];
            }
#pragma unroll
            for (int o = 1; o < 16; o <<= 1) {
                s0 += __shfl_xor(s0, o);
                s1 += __shfl_xor(s1, o);
                d0 += __shfl_xor(d0, o);
                d1 += __shfl_xor(d1, o);
            }
            if (col == 0) {
                const long rg = bm + wm + mt * 16 + q * 4 + r;
                aux[rg * 4 + 0] = s0;
                aux[rg * 4 + 1] = s1;
                aux[rg * 4 + 2] = d0;
                aux[rg * 4 + 3] = d1;
            }
        }
    }
}

// ---------------- GAT attention (4 graphs/block), 16B-vectorized staging + aggregation
#define GPB 4
__global__ __launch_bounds__(256) void k_gat_attn(u16* __restrict__ h,
                                                  const float* __restrict__ aux,
                                                  const float* __restrict__ bias,
                                                  const int* __restrict__ csr,
                                                  int relu_flag) {
    __shared__ __align__(16) u32 hs[GPB * Nn_ * 64];   // [g][n][cp]
    __shared__ float asd[GPB * Nn_ * 4];
    __shared__ float ev[GPB][162];
    __shared__ float mS[GPB][34], dS[GPB][34];
    __shared__ float bvec[128];
    __shared__ int srcS[Ee], dstS[Ee], offS[Nn_ + 1], eidS[Ee];
    const int t = threadIdx.x;
    const long g0 = (long)blockIdx.x * GPB;

    if (t < Ee) { srcS[t] = csr[t]; dstS[t] = csr[Ee + t]; eidS[t] = csr[180 + t]; }
    if (t >= 128 && t < 128 + Nn_ + 1) offS[t - 128] = csr[162 + t - 128];
    if (t < 128) bvec[t] = bias[t];
    {
        const uint4* hg4 = (const uint4*)((const u32*)h + g0 * 1088);
        for (int i = t; i < GPB * Nn_ * 16; i += 256) ((uint4*)hs)[i] = hg4[i];
        const float* ag = aux + g0 * 68;
        for (int i = t; i < GPB * Nn_ * 4; i += 256) asd[i] = ag[i];   // 272 > 256 (r8 bugfix)
    }
    __syncthreads();
    for (int i = t; i < GPB * 162; i += 256) {
        const int g = i / 162, rem = i % 162, e = rem >> 1, hh = rem & 1;
        float v = asd[(g * Nn_ + srcS[e]) * 4 + hh] + asd[(g * Nn_ + dstS[e]) * 4 + 2 + hh];
        ev[g][rem] = (v > 0.f) ? v : 0.2f * v;
    }
    __syncthreads();
    if (t < GPB * 34) {
        const int g = t / 34, rem = t % 34, n = rem >> 1, hh = rem & 1;
        const int p0 = offS[n], p1 = offS[n + 1];
        float m = -1e30f;
        for (int p = p0; p < p1; p++) m = fmaxf(m, ev[g][eidS[p] * 2 + hh]);
        float den = 0.f;
        for (int p = p0; p < p1; p++) den += expf(ev[g][eidS[p] * 2 + hh] - m);
        mS[g][rem] = m;
        dS[g][rem] = den;
    }
    __syncthreads();
    for (int i = t; i < GPB * 162; i += 256) {
        const int g = i / 162, rem = i % 162, e = rem >> 1, hh = rem & 1;
        const int n = dstS[e];
        ev[g][rem] = expf(ev[g][rem] - mS[g][n * 2 + hh]) / (dS[g][n * 2 + hh] + 1e-16f);
    }
    __syncthreads();
    // aggregation: items = (g, n, cq), each covers 8 bf16 columns (one uint4)
    uint4* hgo4 = (uint4*)((u32*)h + g0 * 1088);
    for (int i = t; i < GPB * Nn_ * 16; i += 256) {
        const int g = i / (Nn_ * 16), rem = i % (Nn_ * 16);
        const int n = rem >> 4, cq = rem & 15, hh = cq >> 3;
        const int p0 = offS[n], p1 = offS[n + 1];
        float a[8] = {};
        for (int p = p0; p < p1; p++) {
            const int e = eidS[p];
            const uint4 hv = ((const uint4*)hs)[(g * Nn_ + srcS[e]) * 16 + cq];
            const float al = ev[g][e * 2 + hh];
            a[0] += al * bflo(hv.x); a[1] += al * bfhi(hv.x);
            a[2] += al * bflo(hv.y); a[3] += al * bfhi(hv.y);
            a[4] += al * bflo(hv.z); a[5] += al * bfhi(hv.z);
            a[6] += al * bflo(hv.w); a[7] += al * bfhi(hv.w);
        }
        const int c0 = cq * 8;
#pragma unroll
        for (int m2 = 0; m2 < 8; m2++) {
            a[m2] += bvec[c0 + m2];
            if (relu_flag) a[m2] = fmaxf(a[m2], 0.f);
        }
        uint4 o;
        o.x = (u32)f2bf(a[0]) | ((u32)f2bf(a[1]) << 16);
        o.y = (u32)f2bf(a[2]) | ((u32)f2bf(a[3]) << 16);
        o.z = (u32)f2bf(a[4]) | ((u32)f2bf(a[5]) << 16);
        o.w = (u32)f2bf(a[6]) | ((u32)f2bf(a[7]) << 16);
        hgo4[(g * Nn_ + n) * 16 + cq] = o;
    }
}

// ---------------- bf16 MFMA GEMM: C[M,ldc] = A[M,K]bf16 @ Bt[N,K]bf16^T + b1[n]+b2[n] (fp32)
__global__ __launch_bounds__(256) void k_gemm_mfma(const u16* __restrict__ A,
                                                   const u16* __restrict__ Bt,
                                                   float* __restrict__ Cm,
                                                   const float* __restrict__ b1,
                                                   const float* __restrict__ b2,
                                                   int K, int ldc) {
    __shared__ u16 ldsA[128 * 64];
    __shared__ u16 ldsB[128 * 64];
    const int w = threadIdx.x >> 6;
    const int lane = threadIdx.x & 63;
    const long bm = (long)blockIdx.x * 128;
    const int bn = blockIdx.y * 128;
    const int wm = (w & 1) * 64, wn = (w >> 1) * 64;
    const int q = lane >> 4, col = lane & 15;
    f32x4 acc[4][4] = {};
    for (int k0 = 0; k0 < K; k0 += 64) {
#pragma unroll
        for (int i = 0; i < 4; i++) {
            const int slot = (w * 4 + i) * 64 + lane;
            const int r = slot >> 3, cs = slot & 7;
            const int cg = cs ^ (r & 7);
            async16(A + (bm + r) * (long)K + k0 + cg * 8, ldsA + (w * 4 + i) * 512);
            async16(Bt + (long)(bn + r) * K + k0 + cg * 8, ldsB + (w * 4 + i) * 512);
        }
        __syncthreads();
#pragma unroll
        for (int kk = 0; kk < 2; kk++) {
            bf16x8 af[4], bfr[4];
#pragma unroll
            for (int mt = 0; mt < 4; mt++) {
                const int m = wm + mt * 16 + col;
                const int cs = (kk * 4 + q) ^ (m & 7);
                af[mt] = *(const bf16x8*)&ldsA[m * 64 + cs * 8];
            }
#pragma unroll
            for (int nt = 0; nt < 4; nt++) {
                const int n = wn + nt * 16 + col;
                const int cs = (kk * 4 + q) ^ (n & 7);
                bfr[nt] = *(const bf16x8*)&ldsB[n * 64 + cs * 8];
            }
#pragma unroll
            for (int mt = 0; mt < 4; mt++)
#pragma unroll
                for (int nt = 0; nt < 4; nt++)
                    acc[mt][nt] = __builtin_amdgcn_mfma_f32_16x16x32_bf16(af[mt], bfr[nt], acc[mt][nt], 0, 0, 0);
        }
        __syncthreads();
    }
#pragma unroll
    for (int mt = 0; mt < 4; mt++)
#pragma unroll
        for (int nt = 0; nt < 4; nt++) {
            const int cg = bn + wn + nt * 16 + col;
            const float bb = b1[cg] + b2[cg];
#pragma unroll
            for (int r = 0; r < 4; r++) {
                const long rg = bm + wm + mt * 16 + q * 4 + r;
                Cm[rg * ldc + cg] = acc[mt][nt][r] + bb;
            }
        }
}

// ---------------- LSTM recurrence: f16 packed whh + v_dot2_f32_f16 MAC (r16)
// r15 PMC: VGPR=84 -> allocator keeps only the PACKED 64-reg weight form and re-unpacks
// every step (~96 VALU/step); VALUBusy 57% of 2770cyc/step = issue-bound at ~300 inst.
// Fix: packed-f16 dot2 (v_dot2_f32_f16) consumes the packed pair directly -> MAC is
// 64 dot2 + 16 b128 LDS reads (~90 inst/step). h_s stored packed f16 (f16 h passed
// accuracy-wise in r10/r11 as bf16, f16 is tighter); whh f16 (tighter than passing bf16).
// hseq output stays bf16/fp32. Gate-split nonlinearity + reg c-state + XW prefetch kept.
template <int OBF16>
__global__ __launch_bounds__(512, 1) void k_lstm(const float* __restrict__ XW,
                                                 const u16* __restrict__ whhh,
                                                 void* __restrict__ hseq) {
    const int b = blockIdx.x, j = threadIdx.x;
    u32 wp[64];   // 128 f16 = 64 VGPRs (register-resident, proven at this footprint)
    const u32* wrow = (const u32*)(whhh + (long)j * OUT_);
#pragma unroll
    for (int k = 0; k < 64; k++) wp[k] = wrow[k];
    __shared__ __align__(16) u16 h_sh[OUT_];   // packed f16 h-state (64 u32)
    __shared__ float gate_s[G4];
    float c_r = 0.f;
    if (j < 64) ((u32*)h_sh)[j] = 0;
    float xw = XW[((long)b * Tt + 0) * G4 + j];
    const int gate = j >> 7;   // 0:i 1:f 2:g 3:o
    __syncthreads();
    for (int t = 0; t < Tt; t++) {
        float xw_next = 0.f;
        if (t < Tt - 1) xw_next = XW[((long)b * Tt + t + 1) * G4 + j];
        float a0 = xw, a1 = 0.f, a2 = 0.f, a3 = 0.f;
        const uint4* hv4 = (const uint4*)h_sh;
#pragma unroll
        for (int k = 0; k < 4; k++) {
            const uint4 H0 = hv4[k], H1 = hv4[4 + k], H2 = hv4[8 + k], H3 = hv4[12 + k];
            a0 = dot2acc(wp[4 * k + 0], H0.x, a0);
            a0 = dot2acc(wp[4 * k + 1], H0.y, a0);
            a0 = dot2acc(wp[4 * k + 2], H0.z, a0);
            a0 = dot2acc(wp[4 * k + 3], H0.w, a0);
            a1 = dot2acc(wp[16 + 4 * k + 0], H1.x, a1);
            a1 = dot2acc(wp[16 + 4 * k + 1], H1.y, a1);
            a1 = dot2acc(wp[16 + 4 * k + 2], H1.z, a1);
            a1 = dot2acc(wp[16 + 4 * k + 3], H1.w, a1);
            a2 = dot2acc(wp[32 + 4 * k + 0], H2.x, a2);
            a2 = dot2acc(wp[32 + 4 * k + 1], H2.y, a2);
            a2 = dot2acc(wp[32 + 4 * k + 2], H2.z, a2);
            a2 = dot2acc(wp[32 + 4 * k + 3], H2.w, a2);
            a3 = dot2acc(wp[48 + 4 * k + 0], H3.x, a3);
            a3 = dot2acc(wp[48 + 4 * k + 1], H3.y, a3);
            a3 = dot2acc(wp[48 + 4 * k + 2], H3.z, a3);
            a3 = dot2acc(wp[48 + 4 * k + 3], H3.w, a3);
        }
        const float acc = (a0 + a1) + (a2 + a3);
        gate_s[j] = (gate == 2) ? tanhf(acc) : 1.f / (1.f + expf(-acc));
        __syncthreads();
        if (j < OUT_) {
            const float si = gate_s[j], sf = gate_s[OUT_ + j];
            const float gg = gate_s[2 * OUT_ + j], so = gate_s[3 * OUT_ + j];
            const float c = sf * c_r + si * gg;
            c_r = c;
            const float hh = so * tanhf(c);
            h_sh[j] = f2h(hh);
            const long idx = ((long)b * Tt + t) * OUT_ + j;
            if (OBF16) ((u16*)hseq)[idx] = f2bf(hh);
            else       ((float*)hseq)[idx] = hh;
        }
        xw = xw_next;
        __syncthreads();
    }
}

// ---------------- attention pooling + FC
__global__ __launch_bounds__(64) void k_attn_fc(const float* __restrict__ h2,
                                                const float* __restrict__ attn_w,
                                                const float* __restrict__ attn_b,
                                                const float* __restrict__ fc_w,
                                                const float* __restrict__ fc_b,
                                                float* __restrict__ out) {
    const int b = blockIdx.x, t = threadIdx.x;
    __shared__ float aw[Tt];
    __shared__ float ctx[OUT_];
    const float* hb = h2 + (long)b * Tt * OUT_;
    float acc = 0.f;
    for (int d = 0; d < OUT_; d++) acc += hb[t * OUT_ + d] * attn_w[d];
    float sc = tanhf(acc + attn_b[0]);
    float m = sc;
#pragma unroll
    for (int o = 32; o > 0; o >>= 1) m = fmaxf(m, __shfl_xor(m, o));
    float ex = expf(sc - m);
    float sum = ex;
#pragma unroll
    for (int o = 32; o > 0; o >>= 1) sum += __shfl_xor(sum, o);
    aw[t] = ex / sum;
    __syncthreads();
    for (int d = t; d < OUT_; d += 64) {
        float c = 0.f;
        for (int tt = 0; tt < Tt; tt++) c += aw[tt] * hb[tt * OUT_ + d];
        ctx[d] = c;
    }
    __syncthreads();
    if (t < NCLS) {
        float o = fc_b[t];
        for (int d = 0; d < OUT_; d++) o += ctx[d] * fc_w[t * OUT_ + d];
        out[b * NCLS + t] = o;
    }
}

extern "C" void kernel_launch(void* const* d_in, const int* in_sizes, int n_in,
                              void* d_out, int out_size, void* d_ws, size_t ws_size,
                              hipStream_t stream) {
    const float* x          = (const float*)d_in[0];
    const int*   edge_index = (const int*)d_in[1];
    const float* gw[4]  = {(const float*)d_in[2], (const float*)d_in[6], (const float*)d_in[10], (const float*)d_in[14]};
    const float* gas[4] = {(const float*)d_in[3], (const float*)d_in[7], (const float*)d_in[11], (const float*)d_in[15]};
    const float* gad[4] = {(const float*)d_in[4], (const float*)d_in[8], (const float*)d_in[12], (const float*)d_in[16]};
    const float* gb[4]  = {(const float*)d_in[5], (const float*)d_in[9], (const float*)d_in[13], (const float*)d_in[17]};
    const float* wih0 = (const float*)d_in[18];
    const float* whh0 = (const float*)d_in[19];
    const float* bih0 = (const float*)d_in[20];
    const float* bhh0 = (const float*)d_in[21];
    const float* wih1 = (const float*)d_in[22];
    const float* whh1 = (const float*)d_in[23];
    const float* bih1 = (const float*)d_in[24];
    const float* bhh1 = (const float*)d_in[25];
    const float* attn_w = (const float*)d_in[26];
    const float* attn_b = (const float*)d_in[27];
    const float* fc_w   = (const float*)d_in[28];
    const float* fc_b   = (const float*)d_in[29];
    float* out = (float*)d_out;
    char* p = (char*)d_ws;

    // Workspace (~158.2 MB; 176.2 MB proven OK in round 2)
    u16*   hbuf  = (u16*)(p + 0L);              // 71,303,168 B
    float* aux   = (float*)(p + 71303168L);     //  4,456,448 B
    float* XW0   = (float*)(p + 75759616L);     // 33,554,432 B
    float* XW1   = (float*)(p + 109314048L);    // 33,554,432 B
    float* h2s   = (float*)(p + 142868480L);    //  8,388,608 B
    u16*   h1s   = (u16*)(p + 151257088L);      //  4,194,304 B
    u16*   wih0b = (u16*)(p + 155451392L);      //  2,228,224 B
    u16*   wih1b = (u16*)(p + 157679616L);      //    131,072 B
    u16*   whh0h = (u16*)(p + 157810688L);      //    131,072 B  (f16)
    u16*   whh1h = (u16*)(p + 157941760L);      //    131,072 B  (f16)
    u16*   wt1   = (u16*)(p + 158072832L);      //     32,768 B (x3)
    u16*   wt2   = (u16*)(p + 158105600L);
    u16*   wt3   = (u16*)(p + 158138368L);
    int*   csr   = (int*)(p + 158171136L);      //      1,044 B

    k_setup<<<1, 128, 0, stream>>>(edge_index, csr);
    k_convert_small<<<960, 256, 0, stream>>>(gw[1], gw[2], gw[3], wih1, whh0, whh1,
                                             wt1, wt2, wt3, wih1b, whh0h, whh1h);
    k_convert<<<(512 * 2176 + 255) / 256, 256, 0, stream>>>(wih0, wih0b, 512L * 2176);

    // GAT layer 0 projection (+fp32 attn dots) then attention
    k_l0<<<Mg / 16, 256, 0, stream>>>(x, gw[0], gas[0], gad[0], hbuf, aux);
    k_gat_attn<<<Gg / GPB, 256, 0, stream>>>(hbuf, aux, gb[0], csr, 1);
    // layers 1..3: in-place MFMA GEMM with fp32 dot epilogue, then attention
    k_gemm_gat<<<Mg / 128, 256, 0, stream>>>(hbuf, wt1, gas[1], gad[1], aux);
    k_gat_attn<<<Gg / GPB, 256, 0, stream>>>(hbuf, aux, gb[1], csr, 0);
    k_gemm_gat<<<Mg / 128, 256, 0, stream>>>(hbuf, wt2, gas[2], gad[2], aux);
    k_gat_attn<<<Gg / GPB, 256, 0, stream>>>(hbuf, aux, gb[2], csr, 1);
    k_gemm_gat<<<Mg / 128, 256, 0, stream>>>(hbuf, wt3, gas[3], gad[3], aux);
    k_gat_attn<<<Gg / GPB, 256, 0, stream>>>(hbuf, aux, gb[3], csr, 0);

    // LSTM layer 0: input GEMM (hbuf == lstm_in [16384,2176] bf16) + dot2 recurrence
    k_gemm_mfma<<<dim3(Gg / 128, 4), 256, 0, stream>>>(hbuf, wih0b, XW0, bih0, bhh0, LSTM_IN, G4);
    k_lstm<1><<<Bb, 512, 0, stream>>>(XW0, whh0h, h1s);
    // LSTM layer 1
    k_gemm_mfma<<<dim3(Gg / 128, 4), 256, 0, stream>>>(h1s, wih1b, XW1, bih1, bhh1, OUT_, G4);
    k_lstm<0><<<Bb, 512, 0, stream>>>(XW1, whh1h, h2s);

    k_attn_fc<<<Bb, 64, 0, stream>>>(h2s, attn_w, attn_b, fc_w, fc_b, out);
}